// Round 8
// baseline (131.815 us; speedup 1.0000x reference)
//
#include <hip/hip_runtime.h>
#include <stdint.h>
#include <math.h>

#define MROWS 8192
#define KDIM  512

typedef __attribute__((ext_vector_type(8))) short short8;
typedef __attribute__((ext_vector_type(4))) float f32x4;

#if __has_builtin(__builtin_amdgcn_exp2f)
#define EXP2F(x) __builtin_amdgcn_exp2f(x)
#else
#define EXP2F(x) exp2f(x)
#endif

#define GL2LDS(gp, lp) __builtin_amdgcn_global_load_lds( \
    (__attribute__((address_space(1))) void*)(gp),       \
    (__attribute__((address_space(3))) void*)(lp), 16, 0, 0)

__device__ inline unsigned short f2bf_rne(float f) {
  unsigned u = __builtin_bit_cast(unsigned, f);
  unsigned r = 0x7FFFu + ((u >> 16) & 1u);
  return (unsigned short)((u + r) >> 16);
}

// Swizzle: logical (row, g) -> physical granule within a 1024-granule K-half.
// Verified bijective on-device (R2-R6 validation).
__device__ inline int swzP(int row, int g) {
  return (row * 4) ^ (g ^ (row & 3)) ^ (((row >> 2) & 1) << 2);
}

// ---------------------------------------------------------------------------
// Kernel 1: cast X -> bf16, row norms, partial sums for sigma^2.
// ---------------------------------------------------------------------------
__global__ __launch_bounds__(256) void k_prep(
    const float* __restrict__ X, unsigned short* __restrict__ Xb,
    float* __restrict__ sq, float* __restrict__ svec_part,
    float* __restrict__ sumsq_part) {
  __shared__ float ssv[4][512];
  __shared__ float ssq[4];
  const int tid = threadIdx.x, lane = tid & 63, w = tid >> 6;
  const int b = blockIdx.x;

  float ca[8] = {0.f, 0.f, 0.f, 0.f, 0.f, 0.f, 0.f, 0.f};
  float lss = 0.f;

  for (int rr = 0; rr < 8; ++rr) {
    const int row = b * 32 + w * 8 + rr;
    const float4* xr = (const float4*)(X + (size_t)row * KDIM);
    float4 v0 = xr[lane];
    float4 v1 = xr[64 + lane];

    ushort4 p0, p1;
    p0.x = f2bf_rne(v0.x); p0.y = f2bf_rne(v0.y);
    p0.z = f2bf_rne(v0.z); p0.w = f2bf_rne(v0.w);
    p1.x = f2bf_rne(v1.x); p1.y = f2bf_rne(v1.y);
    p1.z = f2bf_rne(v1.z); p1.w = f2bf_rne(v1.w);
    *(ushort4*)(Xb + (size_t)row * KDIM + lane * 4)       = p0;
    *(ushort4*)(Xb + (size_t)row * KDIM + 256 + lane * 4) = p1;

    float s2 = v0.x*v0.x + v0.y*v0.y + v0.z*v0.z + v0.w*v0.w
             + v1.x*v1.x + v1.y*v1.y + v1.z*v1.z + v1.w*v1.w;
    float rs = s2;
#pragma unroll
    for (int off = 32; off; off >>= 1) rs += __shfl_xor(rs, off, 64);
    if (lane == 0) sq[row] = rs;
    lss += s2;

    ca[0] += v0.x; ca[1] += v0.y; ca[2] += v0.z; ca[3] += v0.w;
    ca[4] += v1.x; ca[5] += v1.y; ca[6] += v1.z; ca[7] += v1.w;
  }

#pragma unroll
  for (int i = 0; i < 4; ++i) {
    ssv[w][lane * 4 + i]       = ca[i];
    ssv[w][256 + lane * 4 + i] = ca[4 + i];
  }
  float wsum = lss;
#pragma unroll
  for (int off = 32; off; off >>= 1) wsum += __shfl_xor(wsum, off, 64);
  if (lane == 0) ssq[w] = wsum;
  __syncthreads();

  svec_part[(size_t)b * 512 + tid] =
      ssv[0][tid] + ssv[1][tid] + ssv[2][tid] + ssv[3][tid];
  svec_part[(size_t)b * 512 + 256 + tid] =
      ssv[0][tid + 256] + ssv[1][tid + 256] + ssv[2][tid + 256] + ssv[3][tid + 256];
  if (tid == 0) sumsq_part[b] = ssq[0] + ssq[1] + ssq[2] + ssq[3];
}

// ---------------------------------------------------------------------------
// Kernel 2: scale = log2e / (2*sigma^2)
// ---------------------------------------------------------------------------
__global__ __launch_bounds__(256) void k_sigma(
    const float* __restrict__ svec_part, const float* __restrict__ sumsq_part,
    float* __restrict__ scale) {
  __shared__ float red[4];
  const int tid = threadIdx.x, lane = tid & 63, w = tid >> 6;
  float s1 = 0.f, s2 = 0.f;
  for (int b = 0; b < 256; ++b) {
    s1 += svec_part[(size_t)b * 512 + tid];
    s2 += svec_part[(size_t)b * 512 + 256 + tid];
  }
  float ss = s1 * s1 + s2 * s2;
#pragma unroll
  for (int off = 32; off; off >>= 1) ss += __shfl_xor(ss, off, 64);
  if (lane == 0) red[w] = ss;
  __syncthreads();
  if (tid == 0) {
    float sst = red[0] + red[1] + red[2] + red[3];
    float sumsq = 0.f;
    for (int b = 0; b < 256; ++b) sumsq += sumsq_part[b];
    const float m = (float)MROWS;
    float meand2 = 2.f * sumsq / m - 2.f * sst / (m * m);
    float sigma2 = 1.0f * meand2;  // ALPHA = 1.0
    scale[0] = 1.4426950408889634f / (2.f * sigma2);
  }
}

// ---------------------------------------------------------------------------
// Kernel 3: SYMMETRIC 256x256-tile 8-phase bf16 MFMA GEMM (loop = R6, proven).
// Epilogue: NO LDS bounce. acc[mf][n] (f32x4 = 4 consecutive out-ROWS of one
// col) = 4 consecutive COLS of one row of the TRANSPOSED tile -> the (bj,bi)
// tile stores directly as dwordx4. Diagonal blocks use only that path (values
// are bitwise-symmetric: same products, same summation order).
// ---------------------------------------------------------------------------
__global__ __launch_bounds__(512, 2) void k_gemm(
    const unsigned short* __restrict__ Xb, const float* __restrict__ sq,
    const float* __restrict__ scale, float* __restrict__ out) {
  __shared__ __align__(16) unsigned short Asm[2 * 16384];
  __shared__ __align__(16) unsigned short Bsm[2 * 16384];

  const int tid = threadIdx.x, lane = tid & 63, w = tid >> 6;
  const int wr = w >> 2, wc = w & 3;  // 2 x 4 wave grid
  const int ln15 = lane & 15, g = lane >> 4;

  // Upper-triangular unranking with XCD swizzle (528 = 8*66, bijective)
  const int blk = blockIdx.x;
  const int t = (blk & 7) * 66 + (blk >> 3);
  int j = (int)((sqrtf(8.0f * (float)t + 1.0f) - 1.0f) * 0.5f);
  while ((j + 1) * (j + 2) / 2 <= t) ++j;
  while (j * (j + 1) / 2 > t) --j;
  const int bi = t - j * (j + 1) / 2;  // bi <= bj
  const int bj = j;

  // stage-source: thread covers physical granules P = w*128 + q*64 + lane
  const unsigned short* XbA = Xb + (size_t)bi * 256 * KDIM;
  const unsigned short* XbB = Xb + (size_t)bj * 256 * KDIM;
  const unsigned short* sA[2];
  const unsigned short* sB[2];
  int dOf[2];
#pragma unroll
  for (int q = 0; q < 2; ++q) {
    const int P = (w << 7) + (q << 6) + lane;
    const int row = ((P >> 3) << 1) | (((P >> 2) ^ (P >> 4)) & 1);
    const int gg = (P & 3) ^ (row & 3);
    sA[q] = XbA + row * KDIM + gg * 8;
    sB[q] = XbB + row * KDIM + gg * 8;
    dOf[q] = (w << 10) + (q << 9);
  }

  // read-side swizzled element offsets within one K-half block
  int eaA[2][4], eaB[4];
#pragma unroll
  for (int mh = 0; mh < 2; ++mh)
#pragma unroll
    for (int m = 0; m < 4; ++m)
      eaA[mh][m] = swzP(wr * 128 + mh * 64 + m * 16 + ln15, g) * 8;
#pragma unroll
  for (int n = 0; n < 4; ++n)
    eaB[n] = swzP(wc * 64 + n * 16 + ln15, g) * 8;

  f32x4 acc[8][4] = {};
  short8 a[4], bfr[4];

#define STG_A(sb, kt, kh)                                                      \
  { GL2LDS(sA[0] + (kt) * 64 + (kh) * 32, &Asm[(sb)*16384 + (kh)*8192 + dOf[0]]); \
    GL2LDS(sA[1] + (kt) * 64 + (kh) * 32, &Asm[(sb)*16384 + (kh)*8192 + dOf[1]]); }
#define STG_B(sb, kt, kh)                                                      \
  { GL2LDS(sB[0] + (kt) * 64 + (kh) * 32, &Bsm[(sb)*16384 + (kh)*8192 + dOf[0]]); \
    GL2LDS(sB[1] + (kt) * 64 + (kh) * 32, &Bsm[(sb)*16384 + (kh)*8192 + dOf[1]]); }

  // prologue: Kt0 -> buf0, full drain
  STG_A(0, 0, 0); STG_B(0, 0, 0); STG_A(0, 0, 1); STG_B(0, 0, 1);
  asm volatile("s_waitcnt vmcnt(0)" ::: "memory");
  __builtin_amdgcn_s_barrier();
  __builtin_amdgcn_sched_barrier(0);

#pragma unroll
  for (int i = 0; i < 4; ++i) {
#pragma unroll
    for (int p = 0; p < 8; ++p) {
      const int rb = (p < 4) ? 0 : 1;      // read buffer
      const int kh = (p >> 1) & 1;         // K-half being computed
      const int mh = p & 1;                // M-half quadrant

#pragma unroll
      for (int m = 0; m < 4; ++m)
        a[m] = *(const short8*)&Asm[rb * 16384 + kh * 8192 + eaA[mh][m]];
      if (mh == 0) {
#pragma unroll
        for (int n = 0; n < 4; ++n)
          bfr[n] = *(const short8*)&Bsm[rb * 16384 + kh * 8192 + eaB[n]];
      }

      // stage exactly 1 half-tile (2 loads/thread) into the other buffer
      const int skt = (p < 4) ? (2 * i + 1) : (2 * i + 2);
      if (skt < 8) {
        const int sb = skt & 1;
        const int half = p & 3;  // 0:A-kh0 1:B-kh0 2:A-kh1 3:B-kh1
        if (half == 0)      STG_A(sb, skt, 0)
        else if (half == 1) STG_B(sb, skt, 0)
        else if (half == 2) STG_A(sb, skt, 1)
        else                STG_B(sb, skt, 1)
      }

      __builtin_amdgcn_s_barrier();        // MID
      asm volatile("s_waitcnt lgkmcnt(0)" ::: "memory");
      __builtin_amdgcn_sched_barrier(0);

      __builtin_amdgcn_s_setprio(1);
#pragma unroll
      for (int m = 0; m < 4; ++m)
#pragma unroll
        for (int n = 0; n < 4; ++n)
          acc[mh * 4 + m][n] = __builtin_amdgcn_mfma_f32_16x16x32_bf16(
              a[m], bfr[n], acc[mh * 4 + m][n], 0, 0, 0);
      __builtin_amdgcn_s_setprio(0);

      // counted wait: phase p-2's loads drained (stage->read distance is 3)
      if (skt < 8) {
        asm volatile("s_waitcnt vmcnt(4)" ::: "memory");
      } else if (p == 4) {
        asm volatile("s_waitcnt vmcnt(0)" ::: "memory");  // tail drain
      }
      __builtin_amdgcn_s_barrier();        // END
      __builtin_amdgcn_sched_barrier(0);
    }
  }

  asm volatile("s_waitcnt vmcnt(0) lgkmcnt(0)" ::: "memory");

  // ---- epilogue: exp2 in place
  const float cs = scale[0];
  const int hi4 = (lane >> 4) * 4;
  const int rbase = bi * 256 + wr * 128 + hi4;
  const int cbase = bj * 256 + wc * 64 + ln15;

  float scol[4];
#pragma unroll
  for (int n = 0; n < 4; ++n) scol[n] = sq[cbase + n * 16];

#pragma unroll
  for (int mf = 0; mf < 8; ++mf) {
#pragma unroll
    for (int r = 0; r < 4; ++r) {
      const float sr = sq[rbase + mf * 16 + r];
#pragma unroll
      for (int n = 0; n < 4; ++n) {
        float d2 = sr + scol[n] - 2.f * acc[mf][n][r];
        d2 = fmaxf(d2, 0.f);
        acc[mf][n][r] = EXP2F(-d2 * cs);
      }
    }
  }

  // ---- store 1: direct tile (bi, bj) as scalar stores (off-diag only;
  // diag tile is fully covered by the transposed dwordx4 path below)
  if (bi != bj) {
#pragma unroll
    for (int mf = 0; mf < 8; ++mf) {
#pragma unroll
      for (int r = 0; r < 4; ++r) {
        const size_t rowoff = (size_t)(rbase + mf * 16 + r) * MROWS;
#pragma unroll
        for (int n = 0; n < 4; ++n)
          out[rowoff + cbase + n * 16] = acc[mf][n][r];
      }
    }
  }

  // ---- store 2: transposed tile (bj, bi) as dwordx4 (16B contiguous:
  // acc[mf][n] = 4 consecutive columns of transposed-row cbase+n*16)
#pragma unroll
  for (int mf = 0; mf < 8; ++mf) {
#pragma unroll
    for (int n = 0; n < 4; ++n) {
      *(float4*)&out[(size_t)(cbase + n * 16) * MROWS + rbase + mf * 16] =
          *(float4*)&acc[mf][n];
    }
  }
}

// ---------------------------------------------------------------------------
extern "C" void kernel_launch(void* const* d_in, const int* in_sizes, int n_in,
                              void* d_out, int out_size, void* d_ws,
                              size_t ws_size, hipStream_t stream) {
  (void)in_sizes; (void)n_in; (void)out_size; (void)ws_size;
  const float* X = (const float*)d_in[0];
  float* out = (float*)d_out;
  char* ws = (char*)d_ws;

  unsigned short* Xb  = (unsigned short*)ws;                      // 8 MB bf16
  float* sq           = (float*)(ws + 8388608);                   // 32 KB
  float* svec_part    = (float*)(ws + 8388608 + 32768);           // 512 KB
  float* sumsq_part   = (float*)(ws + 8388608 + 32768 + 524288);  // 1 KB
  float* scale        = (float*)(ws + 8388608 + 32768 + 524288 + 1024);

  hipLaunchKernelGGL(k_prep, dim3(256), dim3(256), 0, stream,
                     X, Xb, sq, svec_part, sumsq_part);
  hipLaunchKernelGGL(k_sigma, dim3(1), dim3(256), 0, stream,
                     svec_part, sumsq_part, scale);
  hipLaunchKernelGGL(k_gemm, dim3(528), dim3(512), 0, stream,
                     Xb, sq, scale, out);
}

// Round 9
// 114.189 us; speedup vs baseline: 1.1544x; 1.1544x over previous
//
#include <hip/hip_runtime.h>
#include <stdint.h>
#include <math.h>

#define MROWS 8192
#define KDIM  512

typedef __attribute__((ext_vector_type(8))) short short8;
typedef __attribute__((ext_vector_type(4))) float f32x4;

#if __has_builtin(__builtin_amdgcn_exp2f)
#define EXP2F(x) __builtin_amdgcn_exp2f(x)
#else
#define EXP2F(x) exp2f(x)
#endif

#define GL2LDS(gp, lp) __builtin_amdgcn_global_load_lds( \
    (__attribute__((address_space(1))) void*)(gp),       \
    (__attribute__((address_space(3))) void*)(lp), 16, 0, 0)

__device__ inline unsigned short f2bf_rne(float f) {
  unsigned u = __builtin_bit_cast(unsigned, f);
  unsigned r = 0x7FFFu + ((u >> 16) & 1u);
  return (unsigned short)((u + r) >> 16);
}

// Swizzle: logical (row, g) -> physical granule (bijective; verified R2-R7,
// holds on the 512-granule domain: bits2-8 = row-permute, bits0-1 = g^(row&3)).
__device__ inline int swzP(int row, int g) {
  return (row * 4) ^ (g ^ (row & 3)) ^ (((row >> 2) & 1) << 2);
}

// ---------------------------------------------------------------------------
// Kernel 1: cast X -> bf16, row norms, partial sums for sigma^2.
// ---------------------------------------------------------------------------
__global__ __launch_bounds__(256) void k_prep(
    const float* __restrict__ X, unsigned short* __restrict__ Xb,
    float* __restrict__ sq, float* __restrict__ svec_part,
    float* __restrict__ sumsq_part) {
  __shared__ float ssv[4][512];
  __shared__ float ssq[4];
  const int tid = threadIdx.x, lane = tid & 63, w = tid >> 6;
  const int b = blockIdx.x;

  float ca[8] = {0.f, 0.f, 0.f, 0.f, 0.f, 0.f, 0.f, 0.f};
  float lss = 0.f;

  for (int rr = 0; rr < 8; ++rr) {
    const int row = b * 32 + w * 8 + rr;
    const float4* xr = (const float4*)(X + (size_t)row * KDIM);
    float4 v0 = xr[lane];
    float4 v1 = xr[64 + lane];

    ushort4 p0, p1;
    p0.x = f2bf_rne(v0.x); p0.y = f2bf_rne(v0.y);
    p0.z = f2bf_rne(v0.z); p0.w = f2bf_rne(v0.w);
    p1.x = f2bf_rne(v1.x); p1.y = f2bf_rne(v1.y);
    p1.z = f2bf_rne(v1.z); p1.w = f2bf_rne(v1.w);
    *(ushort4*)(Xb + (size_t)row * KDIM + lane * 4)       = p0;
    *(ushort4*)(Xb + (size_t)row * KDIM + 256 + lane * 4) = p1;

    float s2 = v0.x*v0.x + v0.y*v0.y + v0.z*v0.z + v0.w*v0.w
             + v1.x*v1.x + v1.y*v1.y + v1.z*v1.z + v1.w*v1.w;
    float rs = s2;
#pragma unroll
    for (int off = 32; off; off >>= 1) rs += __shfl_xor(rs, off, 64);
    if (lane == 0) sq[row] = rs;
    lss += s2;

    ca[0] += v0.x; ca[1] += v0.y; ca[2] += v0.z; ca[3] += v0.w;
    ca[4] += v1.x; ca[5] += v1.y; ca[6] += v1.z; ca[7] += v1.w;
  }

#pragma unroll
  for (int i = 0; i < 4; ++i) {
    ssv[w][lane * 4 + i]       = ca[i];
    ssv[w][256 + lane * 4 + i] = ca[4 + i];
  }
  float wsum = lss;
#pragma unroll
  for (int off = 32; off; off >>= 1) wsum += __shfl_xor(wsum, off, 64);
  if (lane == 0) ssq[w] = wsum;
  __syncthreads();

  svec_part[(size_t)b * 512 + tid] =
      ssv[0][tid] + ssv[1][tid] + ssv[2][tid] + ssv[3][tid];
  svec_part[(size_t)b * 512 + 256 + tid] =
      ssv[0][tid + 256] + ssv[1][tid + 256] + ssv[2][tid + 256] + ssv[3][tid + 256];
  if (tid == 0) sumsq_part[b] = ssq[0] + ssq[1] + ssq[2] + ssq[3];
}

// ---------------------------------------------------------------------------
// Kernel 2: scale = log2e / (2*sigma^2)
// ---------------------------------------------------------------------------
__global__ __launch_bounds__(256) void k_sigma(
    const float* __restrict__ svec_part, const float* __restrict__ sumsq_part,
    float* __restrict__ scale) {
  __shared__ float red[4];
  const int tid = threadIdx.x, lane = tid & 63, w = tid >> 6;
  float s1 = 0.f, s2 = 0.f;
  for (int b = 0; b < 256; ++b) {
    s1 += svec_part[(size_t)b * 512 + tid];
    s2 += svec_part[(size_t)b * 512 + 256 + tid];
  }
  float ss = s1 * s1 + s2 * s2;
#pragma unroll
  for (int off = 32; off; off >>= 1) ss += __shfl_xor(ss, off, 64);
  if (lane == 0) red[w] = ss;
  __syncthreads();
  if (tid == 0) {
    float sst = red[0] + red[1] + red[2] + red[3];
    float sumsq = 0.f;
    for (int b = 0; b < 256; ++b) sumsq += sumsq_part[b];
    const float m = (float)MROWS;
    float meand2 = 2.f * sumsq / m - 2.f * sst / (m * m);
    float sigma2 = 1.0f * meand2;  // ALPHA = 1.0
    scale[0] = 1.4426950408889634f / (2.f * sigma2);
  }
}

// ---------------------------------------------------------------------------
// Kernel 3: SYMMETRIC 128x128-tile bf16 MFMA GEMM, 2 blocks/CU co-resident.
// 256 threads = 4 waves (2x2), per-wave 64x64 C (acc 64 VGPR). LDS 64 KB:
// 2 buf x (A 128x64 + B 128x64) bf16 in two 32-col K-halves, swizzled.
// 16 phases = 8 K-tiles x 2 K-halves; per phase: 8 ds_read_b128 + 4 stage
// loads + 16-MFMA cluster; self-healing vmcnt(4) (distance 2 phases).
// Grid = 2080 upper-tri pairs (8.125/CU -> fine-grained tail; 2080%8==0).
// ---------------------------------------------------------------------------
__global__ __launch_bounds__(256, 2) void k_gemm(
    const unsigned short* __restrict__ Xb, const float* __restrict__ sq,
    const float* __restrict__ scale, float* __restrict__ out) {
  __shared__ __align__(16) char smem[65536];
  unsigned short* Asm = (unsigned short*)smem;            // [2][2][4096] elem
  unsigned short* Bsm = (unsigned short*)(smem + 32768);
  float* tr = (float*)smem;                               // epilogue bounce

  const int tid = threadIdx.x, lane = tid & 63, w = tid >> 6;
  const int wr = w >> 1, wc = w & 1;  // 2 x 2 wave grid
  const int ln15 = lane & 15, g = lane >> 4;

  // Upper-triangular unranking with XCD swizzle (2080 = 8*260, bijective)
  const int blk = blockIdx.x;
  const int t = (blk & 7) * 260 + (blk >> 3);
  int j = (int)((sqrtf(8.0f * (float)t + 1.0f) - 1.0f) * 0.5f);
  while ((j + 1) * (j + 2) / 2 <= t) ++j;
  while (j * (j + 1) / 2 > t) --j;
  const int bi = t - j * (j + 1) / 2;  // bi <= bj
  const int bj = j;

  // stage-source: thread covers physical granules P = w*128 + q*64 + lane
  // (512 granules per 8 KB K-half; inverse-swizzled global source)
  const unsigned short* XbA = Xb + (size_t)bi * 128 * KDIM;
  const unsigned short* XbB = Xb + (size_t)bj * 128 * KDIM;
  const unsigned short* sA[2];
  const unsigned short* sB[2];
  int dOf[2];
#pragma unroll
  for (int q = 0; q < 2; ++q) {
    const int P = (w << 7) + (q << 6) + lane;
    const int row = ((P >> 3) << 1) | (((P >> 2) ^ (P >> 4)) & 1);
    const int gg = (P & 3) ^ (row & 3);
    sA[q] = XbA + row * KDIM + gg * 8;
    sB[q] = XbB + row * KDIM + gg * 8;
    dOf[q] = (w << 10) + (q << 9);  // element offset within a K-half block
  }

  // read-side swizzled element offsets within one 4096-elem K-half
  int eaA[4], eaB[4];
#pragma unroll
  for (int m = 0; m < 4; ++m)
    eaA[m] = swzP(wr * 64 + m * 16 + ln15, g) * 8;
#pragma unroll
  for (int n = 0; n < 4; ++n)
    eaB[n] = swzP(wc * 64 + n * 16 + ln15, g) * 8;

  f32x4 acc[4][4] = {};
  short8 a[4], bfr[4];

#define STG_A(sb, kt, kh)                                                       \
  { GL2LDS(sA[0] + (kt) * 64 + (kh) * 32, &Asm[(sb)*8192 + (kh)*4096 + dOf[0]]); \
    GL2LDS(sA[1] + (kt) * 64 + (kh) * 32, &Asm[(sb)*8192 + (kh)*4096 + dOf[1]]); }
#define STG_B(sb, kt, kh)                                                       \
  { GL2LDS(sB[0] + (kt) * 64 + (kh) * 32, &Bsm[(sb)*8192 + (kh)*4096 + dOf[0]]); \
    GL2LDS(sB[1] + (kt) * 64 + (kh) * 32, &Bsm[(sb)*8192 + (kh)*4096 + dOf[1]]); }

  // prologue: Kt0 -> buf0 (both K-halves), full drain
  STG_A(0, 0, 0); STG_B(0, 0, 0); STG_A(0, 0, 1); STG_B(0, 0, 1);
  asm volatile("s_waitcnt vmcnt(0)" ::: "memory");
  __builtin_amdgcn_s_barrier();
  __builtin_amdgcn_sched_barrier(0);

#pragma unroll
  for (int i = 0; i < 8; ++i) {
#pragma unroll
    for (int p = 0; p < 2; ++p) {
      const int rb = i & 1;  // read buffer; kh = p

#pragma unroll
      for (int m = 0; m < 4; ++m)
        a[m] = *(const short8*)&Asm[rb * 8192 + p * 4096 + eaA[m]];
#pragma unroll
      for (int n = 0; n < 4; ++n)
        bfr[n] = *(const short8*)&Bsm[rb * 8192 + p * 4096 + eaB[n]];

      // stage K-half p of tile i+1 into the other buffer (4 loads/thread)
      if (i < 7) {
        const int sb = (i + 1) & 1;
        STG_A(sb, i + 1, p);
        STG_B(sb, i + 1, p);
      }

      __builtin_amdgcn_s_barrier();        // MID
      asm volatile("s_waitcnt lgkmcnt(0)" ::: "memory");
      __builtin_amdgcn_sched_barrier(0);

      __builtin_amdgcn_s_setprio(1);
#pragma unroll
      for (int m = 0; m < 4; ++m)
#pragma unroll
        for (int n = 0; n < 4; ++n)
          acc[m][n] = __builtin_amdgcn_mfma_f32_16x16x32_bf16(
              a[m], bfr[n], acc[m][n], 0, 0, 0);
      __builtin_amdgcn_s_setprio(0);

      // self-healing counted wait: with 4 loads/phase, vmcnt(4) guarantees
      // the previous phase's stage has landed (read distance = 2 phases).
      if (i < 7) {
        asm volatile("s_waitcnt vmcnt(4)" ::: "memory");
      } else if (p == 0) {
        asm volatile("s_waitcnt vmcnt(0)" ::: "memory");  // tail drain
      }
      __builtin_amdgcn_s_barrier();        // END
      __builtin_amdgcn_sched_barrier(0);
    }
  }

  asm volatile("s_waitcnt vmcnt(0) lgkmcnt(0)" ::: "memory");

  // ---- epilogue: exp2 in place
  const float cs = scale[0];
  const int hi4 = g * 4;
  const int rbase = bi * 128 + wr * 64 + hi4;
  const int cbase = bj * 128 + wc * 64 + ln15;

  float scol[4];
#pragma unroll
  for (int n = 0; n < 4; ++n) scol[n] = sq[cbase + n * 16];

#pragma unroll
  for (int m = 0; m < 4; ++m) {
#pragma unroll
    for (int r = 0; r < 4; ++r) {
      const float sr = sq[rbase + m * 16 + r];
#pragma unroll
      for (int n = 0; n < 4; ++n) {
        float d2 = sr + scol[n] - 2.f * acc[m][n][r];
        d2 = fmaxf(d2, 0.f);
        acc[m][n][r] = EXP2F(-d2 * cs);
      }
    }
  }

  // ---- store 1: direct tile (bi, bj), scalar stores (R4-proven pattern)
#pragma unroll
  for (int m = 0; m < 4; ++m) {
#pragma unroll
    for (int r = 0; r < 4; ++r) {
      const size_t rowoff = (size_t)(rbase + m * 16 + r) * MROWS;
#pragma unroll
      for (int n = 0; n < 4; ++n)
        out[rowoff + cbase + n * 16] = acc[m][n][r];
    }
  }

  // ---- store 2: transposed tile (bj, bi) via LDS bounce (off-diag only)
  if (bi != bj) {
#pragma unroll 1
    for (int cc = 0; cc < 2; ++cc) {       // two 64-col chunks of the T-tile
      __syncthreads();
      if (wc == cc) {                       // 2 waves own this chunk
#pragma unroll
        for (int m = 0; m < 4; ++m) {
#pragma unroll
          for (int n = 0; n < 4; ++n) {
            const int c_loc = n * 16 + ln15;           // 0..63
            const int r_loc = wr * 64 + m * 16 + hi4;  // 0..127, %4==0
            *(float4*)&tr[c_loc * 132 + r_loc] = *(float4*)&acc[m][n];
          }
        }
      }
      __syncthreads();
#pragma unroll
      for (int rr = 0; rr < 16; ++rr) {     // 4 waves x 16 rows
        const int row = w * 16 + rr;
        float2 v = *(const float2*)&tr[row * 132 + lane * 2];
        *(float2*)&out[(size_t)(bj * 128 + cc * 64 + row) * MROWS +
                       bi * 128 + lane * 2] = v;
      }
    }
  }
}

// ---------------------------------------------------------------------------
extern "C" void kernel_launch(void* const* d_in, const int* in_sizes, int n_in,
                              void* d_out, int out_size, void* d_ws,
                              size_t ws_size, hipStream_t stream) {
  (void)in_sizes; (void)n_in; (void)out_size; (void)ws_size;
  const float* X = (const float*)d_in[0];
  float* out = (float*)d_out;
  char* ws = (char*)d_ws;

  unsigned short* Xb  = (unsigned short*)ws;                      // 8 MB bf16
  float* sq           = (float*)(ws + 8388608);                   // 32 KB
  float* svec_part    = (float*)(ws + 8388608 + 32768);           // 512 KB
  float* sumsq_part   = (float*)(ws + 8388608 + 32768 + 524288);  // 1 KB
  float* scale        = (float*)(ws + 8388608 + 32768 + 524288 + 1024);

  hipLaunchKernelGGL(k_prep, dim3(256), dim3(256), 0, stream,
                     X, Xb, sq, svec_part, sumsq_part);
  hipLaunchKernelGGL(k_sigma, dim3(1), dim3(256), 0, stream,
                     svec_part, sumsq_part, scale);
  hipLaunchKernelGGL(k_gemm, dim3(2080), dim3(256), 0, stream,
                     Xb, sq, scale, out);
}

// Round 11
// 108.148 us; speedup vs baseline: 1.2188x; 1.0559x over previous
//
#include <hip/hip_runtime.h>
#include <stdint.h>
#include <math.h>

#define MROWS 8192
#define KDIM  512

typedef __attribute__((ext_vector_type(8))) short short8;
typedef __attribute__((ext_vector_type(4))) float f32x4;

#if __has_builtin(__builtin_amdgcn_exp2f)
#define EXP2F(x) __builtin_amdgcn_exp2f(x)
#else
#define EXP2F(x) exp2f(x)
#endif

#define GL2LDS(gp, lp) __builtin_amdgcn_global_load_lds( \
    (__attribute__((address_space(1))) void*)(gp),       \
    (__attribute__((address_space(3))) void*)(lp), 16, 0, 0)

__device__ inline unsigned short f2bf_rne(float f) {
  unsigned u = __builtin_bit_cast(unsigned, f);
  unsigned r = 0x7FFFu + ((u >> 16) & 1u);
  return (unsigned short)((u + r) >> 16);
}

// Swizzle: logical (row, g) -> physical granule in a 512-granule K-step tile.
// Bijective (verified on-device R2-R8).
__device__ inline int swzP(int row, int g) {
  return (row * 4) ^ (g ^ (row & 3)) ^ (((row >> 2) & 1) << 2);
}

// ---------------------------------------------------------------------------
// Kernel 1: cast X -> bf16, row norms, partial sums for sigma^2.
// ---------------------------------------------------------------------------
__global__ __launch_bounds__(256) void k_prep(
    const float* __restrict__ X, unsigned short* __restrict__ Xb,
    float* __restrict__ sq, float* __restrict__ svec_part,
    float* __restrict__ sumsq_part) {
  __shared__ float ssv[4][512];
  __shared__ float ssq[4];
  const int tid = threadIdx.x, lane = tid & 63, w = tid >> 6;
  const int b = blockIdx.x;

  float ca[8] = {0.f, 0.f, 0.f, 0.f, 0.f, 0.f, 0.f, 0.f};
  float lss = 0.f;

  for (int rr = 0; rr < 8; ++rr) {
    const int row = b * 32 + w * 8 + rr;
    const float4* xr = (const float4*)(X + (size_t)row * KDIM);
    float4 v0 = xr[lane];
    float4 v1 = xr[64 + lane];

    ushort4 p0, p1;
    p0.x = f2bf_rne(v0.x); p0.y = f2bf_rne(v0.y);
    p0.z = f2bf_rne(v0.z); p0.w = f2bf_rne(v0.w);
    p1.x = f2bf_rne(v1.x); p1.y = f2bf_rne(v1.y);
    p1.z = f2bf_rne(v1.z); p1.w = f2bf_rne(v1.w);
    *(ushort4*)(Xb + (size_t)row * KDIM + lane * 4)       = p0;
    *(ushort4*)(Xb + (size_t)row * KDIM + 256 + lane * 4) = p1;

    float s2 = v0.x*v0.x + v0.y*v0.y + v0.z*v0.z + v0.w*v0.w
             + v1.x*v1.x + v1.y*v1.y + v1.z*v1.z + v1.w*v1.w;
    float rs = s2;
#pragma unroll
    for (int off = 32; off; off >>= 1) rs += __shfl_xor(rs, off, 64);
    if (lane == 0) sq[row] = rs;
    lss += s2;

    ca[0] += v0.x; ca[1] += v0.y; ca[2] += v0.z; ca[3] += v0.w;
    ca[4] += v1.x; ca[5] += v1.y; ca[6] += v1.z; ca[7] += v1.w;
  }

#pragma unroll
  for (int i = 0; i < 4; ++i) {
    ssv[w][lane * 4 + i]       = ca[i];
    ssv[w][256 + lane * 4 + i] = ca[4 + i];
  }
  float wsum = lss;
#pragma unroll
  for (int off = 32; off; off >>= 1) wsum += __shfl_xor(wsum, off, 64);
  if (lane == 0) ssq[w] = wsum;
  __syncthreads();

  svec_part[(size_t)b * 512 + tid] =
      ssv[0][tid] + ssv[1][tid] + ssv[2][tid] + ssv[3][tid];
  svec_part[(size_t)b * 512 + 256 + tid] =
      ssv[0][tid + 256] + ssv[1][tid + 256] + ssv[2][tid + 256] + ssv[3][tid + 256];
  if (tid == 0) sumsq_part[b] = ssq[0] + ssq[1] + ssq[2] + ssq[3];
}

// ---------------------------------------------------------------------------
// Kernel 2a: first-stage reduction of partials (64 blocks x 4 each)
// ---------------------------------------------------------------------------
__global__ __launch_bounds__(512) void k_sig_a(
    const float* __restrict__ svec_part, const float* __restrict__ sumsq_part,
    float* __restrict__ svec2, float* __restrict__ sumsq2) {
  const int tid = threadIdx.x, b = blockIdx.x;
  float s = 0.f;
#pragma unroll
  for (int k = 0; k < 4; ++k)
    s += svec_part[(size_t)(b * 4 + k) * 512 + tid];
  svec2[(size_t)b * 512 + tid] = s;
  if (tid == 0)
    sumsq2[b] = sumsq_part[b * 4] + sumsq_part[b * 4 + 1] +
                sumsq_part[b * 4 + 2] + sumsq_part[b * 4 + 3];
}

// ---------------------------------------------------------------------------
// Kernel 2b: scale = log2e / (2*sigma^2)
// ---------------------------------------------------------------------------
__global__ __launch_bounds__(256) void k_sigma(
    const float* __restrict__ svec2, const float* __restrict__ sumsq2,
    float* __restrict__ scale) {
  __shared__ float red[4];
  const int tid = threadIdx.x, lane = tid & 63, w = tid >> 6;
  float s1 = 0.f, s2 = 0.f;
#pragma unroll 4
  for (int b = 0; b < 64; ++b) {
    s1 += svec2[(size_t)b * 512 + tid];
    s2 += svec2[(size_t)b * 512 + 256 + tid];
  }
  float ss = s1 * s1 + s2 * s2;
#pragma unroll
  for (int off = 32; off; off >>= 1) ss += __shfl_xor(ss, off, 64);
  if (lane == 0) red[w] = ss;
  __syncthreads();
  if (tid == 0) {
    float sst = red[0] + red[1] + red[2] + red[3];
    float sumsq = 0.f;
#pragma unroll
    for (int b = 0; b < 64; ++b) sumsq += sumsq2[b];
    const float m = (float)MROWS;
    float meand2 = 2.f * sumsq / m - 2.f * sst / (m * m);
    float sigma2 = 1.0f * meand2;  // ALPHA = 1.0
    scale[0] = 1.4426950408889634f / (2.f * sigma2);
  }
}

// ---------------------------------------------------------------------------
// Kernel 3: SYMMETRIC 128x128-tile bf16 MFMA GEMM, 3 blocks/CU co-resident.
// BK=32, 16 phases, RING-3 LDS (48 KB): phase i computes buf[i%3], stages
// tile i+2 into buf[(i+2)%3]. Per-phase shape identical to R8 (proven):
// 8 ds_read_b128 + 4 stage loads + 16-MFMA cluster. vmcnt(4)/phase
// (drains phase i-1's loads = tile i+1, read at phase i+1); vmcnt(0) @ i=14.
// WAR on ring slot fenced by phase i-1's lgkmcnt(0) + END barrier.
// ---------------------------------------------------------------------------
__global__ __launch_bounds__(256, 3) void k_gemm(
    const unsigned short* __restrict__ Xb, const float* __restrict__ sq,
    const float* __restrict__ scale, float* __restrict__ out) {
  __shared__ __align__(16) char smem[49152];
  unsigned short* Asm = (unsigned short*)smem;            // [3][4096] elem
  unsigned short* Bsm = (unsigned short*)(smem + 24576);  // [3][4096] elem
  float* tr = (float*)smem;                               // epilogue bounce

  const int tid = threadIdx.x, lane = tid & 63, w = tid >> 6;
  const int wr = w >> 1, wc = w & 1;  // 2 x 2 wave grid
  const int ln15 = lane & 15, g = lane >> 4;

  // Upper-triangular unranking with XCD swizzle (2080 = 8*260, bijective)
  const int blk = blockIdx.x;
  const int t = (blk & 7) * 260 + (blk >> 3);
  int j = (int)((sqrtf(8.0f * (float)t + 1.0f) - 1.0f) * 0.5f);
  while ((j + 1) * (j + 2) / 2 <= t) ++j;
  while (j * (j + 1) / 2 > t) --j;
  const int bi = t - j * (j + 1) / 2;  // bi <= bj
  const int bj = j;

  // stage-source: thread covers physical granules P = w*128 + q*64 + lane
  // (512 granules per 8 KB K-step tile; inverse-swizzled global source)
  const unsigned short* XbA = Xb + (size_t)bi * 128 * KDIM;
  const unsigned short* XbB = Xb + (size_t)bj * 128 * KDIM;
  const unsigned short* sA[2];
  const unsigned short* sB[2];
  int dOf[2];
#pragma unroll
  for (int q = 0; q < 2; ++q) {
    const int P = (w << 7) + (q << 6) + lane;
    const int row = ((P >> 3) << 1) | (((P >> 2) ^ (P >> 4)) & 1);
    const int gg = (P & 3) ^ (row & 3);
    sA[q] = XbA + row * KDIM + gg * 8;
    sB[q] = XbB + row * KDIM + gg * 8;
    dOf[q] = (w << 10) + (q << 9);  // element offset within one ring slot
  }

  // read-side swizzled element offsets within one 4096-elem tile
  int eaA[4], eaB[4];
#pragma unroll
  for (int m = 0; m < 4; ++m)
    eaA[m] = swzP(wr * 64 + m * 16 + ln15, g) * 8;
#pragma unroll
  for (int n = 0; n < 4; ++n)
    eaB[n] = swzP(wc * 64 + n * 16 + ln15, g) * 8;

  f32x4 acc[4][4] = {};
  short8 a[4], bfr[4];

#define STG_A(sb, kt)                                          \
  { GL2LDS(sA[0] + (kt) * 32, &Asm[(sb) * 4096 + dOf[0]]);     \
    GL2LDS(sA[1] + (kt) * 32, &Asm[(sb) * 4096 + dOf[1]]); }
#define STG_B(sb, kt)                                          \
  { GL2LDS(sB[0] + (kt) * 32, &Bsm[(sb) * 4096 + dOf[0]]);     \
    GL2LDS(sB[1] + (kt) * 32, &Bsm[(sb) * 4096 + dOf[1]]); }

  // prologue: stage tiles 0,1; drain tile 0 only (tile 1 stays in flight)
  STG_A(0, 0); STG_B(0, 0);
  STG_A(1, 1); STG_B(1, 1);
  asm volatile("s_waitcnt vmcnt(4)" ::: "memory");
  __builtin_amdgcn_s_barrier();
  __builtin_amdgcn_sched_barrier(0);

#pragma unroll
  for (int i = 0; i < 16; ++i) {
    const int rb = i % 3;  // compile-time after unroll

#pragma unroll
    for (int m = 0; m < 4; ++m)
      a[m] = *(const short8*)&Asm[rb * 4096 + eaA[m]];
#pragma unroll
    for (int n = 0; n < 4; ++n)
      bfr[n] = *(const short8*)&Bsm[rb * 4096 + eaB[n]];

    // stage tile i+2 into ring slot (i+2)%3 (4 loads/thread)
    if (i < 14) {
      const int sb = (i + 2) % 3;
      STG_A(sb, i + 2);
      STG_B(sb, i + 2);
    }

    __builtin_amdgcn_s_barrier();        // MID
    asm volatile("s_waitcnt lgkmcnt(0)" ::: "memory");
    __builtin_amdgcn_sched_barrier(0);

    __builtin_amdgcn_s_setprio(1);
#pragma unroll
    for (int m = 0; m < 4; ++m)
#pragma unroll
      for (int n = 0; n < 4; ++n)
        acc[m][n] = __builtin_amdgcn_mfma_f32_16x16x32_bf16(
            a[m], bfr[n], acc[m][n], 0, 0, 0);
    __builtin_amdgcn_s_setprio(0);

    // counted wait: drains phase i-1's loads (= tile i+1, read next phase)
    if (i < 14) {
      asm volatile("s_waitcnt vmcnt(4)" ::: "memory");
    } else if (i == 14) {
      asm volatile("s_waitcnt vmcnt(0)" ::: "memory");  // tail drain
    }
    __builtin_amdgcn_s_barrier();        // END
    __builtin_amdgcn_sched_barrier(0);
  }

  asm volatile("s_waitcnt vmcnt(0) lgkmcnt(0)" ::: "memory");

  // ---- epilogue: exp2 in place
  const float cs = scale[0];
  const int hi4 = g * 4;
  const int rbase = bi * 128 + wr * 64 + hi4;
  const int cbase = bj * 128 + wc * 64 + ln15;

  float scol[4];
#pragma unroll
  for (int n = 0; n < 4; ++n) scol[n] = sq[cbase + n * 16];

#pragma unroll
  for (int m = 0; m < 4; ++m) {
#pragma unroll
    for (int r = 0; r < 4; ++r) {
      const float sr = sq[rbase + m * 16 + r];
#pragma unroll
      for (int n = 0; n < 4; ++n) {
        float d2 = sr + scol[n] - 2.f * acc[m][n][r];
        d2 = fmaxf(d2, 0.f);
        acc[m][n][r] = EXP2F(-d2 * cs);
      }
    }
  }

  // ---- store 1: direct tile (bi, bj), scalar stores (R4/R8-proven)
#pragma unroll
  for (int m = 0; m < 4; ++m) {
#pragma unroll
    for (int r = 0; r < 4; ++r) {
      const size_t rowoff = (size_t)(rbase + m * 16 + r) * MROWS;
#pragma unroll
      for (int n = 0; n < 4; ++n)
        out[rowoff + cbase + n * 16] = acc[m][n][r];
    }
  }

  // ---- store 2: transposed tile (bj, bi) via LDS bounce (off-diag only)
  if (bi != bj) {
#pragma unroll 1
    for (int cc = 0; cc < 2; ++cc) {       // two 64-col chunks of the T-tile
      __syncthreads();
      if (wc == cc) {                       // 2 waves own this chunk
#pragma unroll
        for (int m = 0; m < 4; ++m) {
#pragma unroll
          for (int n = 0; n < 4; ++n) {
            const int c_loc = n * 16 + ln15;           // 0..63
            const int r_loc = wr * 64 + m * 16 + hi4;  // 0..127, %4==0
            *(float4*)&tr[c_loc * 132 + r_loc] = *(float4*)&acc[m][n];
          }
        }
      }
      __syncthreads();
#pragma unroll
      for (int rr = 0; rr < 16; ++rr) {     // 4 waves x 16 rows
        const int row = w * 16 + rr;
        float2 v = *(const float2*)&tr[row * 132 + lane * 2];
        *(float2*)&out[(size_t)(bj * 128 + cc * 64 + row) * MROWS +
                       bi * 128 + lane * 2] = v;
      }
    }
  }
}

// ---------------------------------------------------------------------------
extern "C" void kernel_launch(void* const* d_in, const int* in_sizes, int n_in,
                              void* d_out, int out_size, void* d_ws,
                              size_t ws_size, hipStream_t stream) {
  (void)in_sizes; (void)n_in; (void)out_size; (void)ws_size;
  const float* X = (const float*)d_in[0];
  float* out = (float*)d_out;
  char* ws = (char*)d_ws;

  // ws layout (non-overlapping; R9's bug was sumsq_part/svec2 inside svec_part)
  unsigned short* Xb  = (unsigned short*)ws;               // [0, 8388608)
  float* sq           = (float*)(ws + 8388608);            // [8388608, 8421376)
  float* svec_part    = (float*)(ws + 8421376);            // [8421376, 8945664)
  float* sumsq_part   = (float*)(ws + 8945664);            // [8945664, 8946688)
  float* svec2        = (float*)(ws + 8946688);            // [8946688, 9077760)
  float* sumsq2       = (float*)(ws + 9077760);            // [9077760, 9078016)
  float* scale        = (float*)(ws + 9078016);            // [9078016, ...)

  hipLaunchKernelGGL(k_prep, dim3(256), dim3(256), 0, stream,
                     X, Xb, sq, svec_part, sumsq_part);
  hipLaunchKernelGGL(k_sig_a, dim3(64), dim3(512), 0, stream,
                     svec_part, sumsq_part, svec2, sumsq2);
  hipLaunchKernelGGL(k_sigma, dim3(1), dim3(256), 0, stream,
                     svec2, sumsq2, scale);
  hipLaunchKernelGGL(k_gemm, dim3(2080), dim3(256), 0, stream,
                     Xb, sq, scale, out);
}

// Round 12
// 106.882 us; speedup vs baseline: 1.2333x; 1.0119x over previous
//
#include <hip/hip_runtime.h>
#include <stdint.h>
#include <math.h>

#define MROWS 8192
#define KDIM  512

typedef __attribute__((ext_vector_type(8))) short short8;
typedef __attribute__((ext_vector_type(4))) float f32x4;
typedef __attribute__((ext_vector_type(2))) float f32x2;

#if __has_builtin(__builtin_amdgcn_exp2f)
#define EXP2F(x) __builtin_amdgcn_exp2f(x)
#else
#define EXP2F(x) exp2f(x)
#endif

#define GL2LDS(gp, lp) __builtin_amdgcn_global_load_lds( \
    (__attribute__((address_space(1))) void*)(gp),       \
    (__attribute__((address_space(3))) void*)(lp), 16, 0, 0)

__device__ inline unsigned short f2bf_rne(float f) {
  unsigned u = __builtin_bit_cast(unsigned, f);
  unsigned r = 0x7FFFu + ((u >> 16) & 1u);
  return (unsigned short)((u + r) >> 16);
}

// Swizzle: logical (row, g) -> physical granule in a 512-granule K-step tile.
// Bijective (verified on-device R2-R10).
__device__ inline int swzP(int row, int g) {
  return (row * 4) ^ (g ^ (row & 3)) ^ (((row >> 2) & 1) << 2);
}

// ---------------------------------------------------------------------------
// Kernel 1: cast X -> bf16, row norms, partial sums for sigma^2.
// ---------------------------------------------------------------------------
__global__ __launch_bounds__(256) void k_prep(
    const float* __restrict__ X, unsigned short* __restrict__ Xb,
    float* __restrict__ sq, float* __restrict__ svec_part,
    float* __restrict__ sumsq_part) {
  __shared__ float ssv[4][512];
  __shared__ float ssq[4];
  const int tid = threadIdx.x, lane = tid & 63, w = tid >> 6;
  const int b = blockIdx.x;

  float ca[8] = {0.f, 0.f, 0.f, 0.f, 0.f, 0.f, 0.f, 0.f};
  float lss = 0.f;

  for (int rr = 0; rr < 8; ++rr) {
    const int row = b * 32 + w * 8 + rr;
    const float4* xr = (const float4*)(X + (size_t)row * KDIM);
    float4 v0 = xr[lane];
    float4 v1 = xr[64 + lane];

    ushort4 p0, p1;
    p0.x = f2bf_rne(v0.x); p0.y = f2bf_rne(v0.y);
    p0.z = f2bf_rne(v0.z); p0.w = f2bf_rne(v0.w);
    p1.x = f2bf_rne(v1.x); p1.y = f2bf_rne(v1.y);
    p1.z = f2bf_rne(v1.z); p1.w = f2bf_rne(v1.w);
    *(ushort4*)(Xb + (size_t)row * KDIM + lane * 4)       = p0;
    *(ushort4*)(Xb + (size_t)row * KDIM + 256 + lane * 4) = p1;

    float s2 = v0.x*v0.x + v0.y*v0.y + v0.z*v0.z + v0.w*v0.w
             + v1.x*v1.x + v1.y*v1.y + v1.z*v1.z + v1.w*v1.w;
    float rs = s2;
#pragma unroll
    for (int off = 32; off; off >>= 1) rs += __shfl_xor(rs, off, 64);
    if (lane == 0) sq[row] = rs;
    lss += s2;

    ca[0] += v0.x; ca[1] += v0.y; ca[2] += v0.z; ca[3] += v0.w;
    ca[4] += v1.x; ca[5] += v1.y; ca[6] += v1.z; ca[7] += v1.w;
  }

#pragma unroll
  for (int i = 0; i < 4; ++i) {
    ssv[w][lane * 4 + i]       = ca[i];
    ssv[w][256 + lane * 4 + i] = ca[4 + i];
  }
  float wsum = lss;
#pragma unroll
  for (int off = 32; off; off >>= 1) wsum += __shfl_xor(wsum, off, 64);
  if (lane == 0) ssq[w] = wsum;
  __syncthreads();

  svec_part[(size_t)b * 512 + tid] =
      ssv[0][tid] + ssv[1][tid] + ssv[2][tid] + ssv[3][tid];
  svec_part[(size_t)b * 512 + 256 + tid] =
      ssv[0][tid + 256] + ssv[1][tid + 256] + ssv[2][tid + 256] + ssv[3][tid + 256];
  if (tid == 0) sumsq_part[b] = ssq[0] + ssq[1] + ssq[2] + ssq[3];
}

// ---------------------------------------------------------------------------
// Kernel 2a: first-stage reduction of partials (64 blocks x 4 each)
// ---------------------------------------------------------------------------
__global__ __launch_bounds__(512) void k_sig_a(
    const float* __restrict__ svec_part, const float* __restrict__ sumsq_part,
    float* __restrict__ svec2, float* __restrict__ sumsq2) {
  const int tid = threadIdx.x, b = blockIdx.x;
  float s = 0.f;
#pragma unroll
  for (int k = 0; k < 4; ++k)
    s += svec_part[(size_t)(b * 4 + k) * 512 + tid];
  svec2[(size_t)b * 512 + tid] = s;
  if (tid == 0)
    sumsq2[b] = sumsq_part[b * 4] + sumsq_part[b * 4 + 1] +
                sumsq_part[b * 4 + 2] + sumsq_part[b * 4 + 3];
}

// ---------------------------------------------------------------------------
// Kernel 2b: scale = log2e / (2*sigma^2)
// ---------------------------------------------------------------------------
__global__ __launch_bounds__(256) void k_sigma(
    const float* __restrict__ svec2, const float* __restrict__ sumsq2,
    float* __restrict__ scale) {
  __shared__ float red[4];
  const int tid = threadIdx.x, lane = tid & 63, w = tid >> 6;
  float s1 = 0.f, s2 = 0.f;
#pragma unroll 4
  for (int b = 0; b < 64; ++b) {
    s1 += svec2[(size_t)b * 512 + tid];
    s2 += svec2[(size_t)b * 512 + 256 + tid];
  }
  float ss = s1 * s1 + s2 * s2;
#pragma unroll
  for (int off = 32; off; off >>= 1) ss += __shfl_xor(ss, off, 64);
  if (lane == 0) red[w] = ss;
  __syncthreads();
  if (tid == 0) {
    float sst = red[0] + red[1] + red[2] + red[3];
    float sumsq = 0.f;
#pragma unroll
    for (int b = 0; b < 64; ++b) sumsq += sumsq2[b];
    const float m = (float)MROWS;
    float meand2 = 2.f * sumsq / m - 2.f * sst / (m * m);
    float sigma2 = 1.0f * meand2;  // ALPHA = 1.0
    scale[0] = 1.4426950408889634f / (2.f * sigma2);
  }
}

// ---------------------------------------------------------------------------
// Kernel 3: SYMMETRIC 128x128-tile bf16 MFMA GEMM, 3 blocks/CU, ring-3 LDS
// (R10-proven loop). Epilogue stores are NONTEMPORAL (nt): output is
// write-once/never-read -> stream around L2, keep Xb/sq resident.
// ---------------------------------------------------------------------------
__global__ __launch_bounds__(256, 3) void k_gemm(
    const unsigned short* __restrict__ Xb, const float* __restrict__ sq,
    const float* __restrict__ scale, float* __restrict__ out) {
  __shared__ __align__(16) char smem[49152];
  unsigned short* Asm = (unsigned short*)smem;            // [3][4096] elem
  unsigned short* Bsm = (unsigned short*)(smem + 24576);  // [3][4096] elem
  float* tr = (float*)smem;                               // epilogue bounce

  const int tid = threadIdx.x, lane = tid & 63, w = tid >> 6;
  const int wr = w >> 1, wc = w & 1;  // 2 x 2 wave grid
  const int ln15 = lane & 15, g = lane >> 4;

  // Upper-triangular unranking with XCD swizzle (2080 = 8*260, bijective)
  const int blk = blockIdx.x;
  const int t = (blk & 7) * 260 + (blk >> 3);
  int j = (int)((sqrtf(8.0f * (float)t + 1.0f) - 1.0f) * 0.5f);
  while ((j + 1) * (j + 2) / 2 <= t) ++j;
  while (j * (j + 1) / 2 > t) --j;
  const int bi = t - j * (j + 1) / 2;  // bi <= bj
  const int bj = j;

  // stage-source: thread covers physical granules P = w*128 + q*64 + lane
  const unsigned short* XbA = Xb + (size_t)bi * 128 * KDIM;
  const unsigned short* XbB = Xb + (size_t)bj * 128 * KDIM;
  const unsigned short* sA[2];
  const unsigned short* sB[2];
  int dOf[2];
#pragma unroll
  for (int q = 0; q < 2; ++q) {
    const int P = (w << 7) + (q << 6) + lane;
    const int row = ((P >> 3) << 1) | (((P >> 2) ^ (P >> 4)) & 1);
    const int gg = (P & 3) ^ (row & 3);
    sA[q] = XbA + row * KDIM + gg * 8;
    sB[q] = XbB + row * KDIM + gg * 8;
    dOf[q] = (w << 10) + (q << 9);  // element offset within one ring slot
  }

  // read-side swizzled element offsets within one 4096-elem tile
  int eaA[4], eaB[4];
#pragma unroll
  for (int m = 0; m < 4; ++m)
    eaA[m] = swzP(wr * 64 + m * 16 + ln15, g) * 8;
#pragma unroll
  for (int n = 0; n < 4; ++n)
    eaB[n] = swzP(wc * 64 + n * 16 + ln15, g) * 8;

  f32x4 acc[4][4] = {};
  short8 a[4], bfr[4];

#define STG_A(sb, kt)                                          \
  { GL2LDS(sA[0] + (kt) * 32, &Asm[(sb) * 4096 + dOf[0]]);     \
    GL2LDS(sA[1] + (kt) * 32, &Asm[(sb) * 4096 + dOf[1]]); }
#define STG_B(sb, kt)                                          \
  { GL2LDS(sB[0] + (kt) * 32, &Bsm[(sb) * 4096 + dOf[0]]);     \
    GL2LDS(sB[1] + (kt) * 32, &Bsm[(sb) * 4096 + dOf[1]]); }

  // prologue: stage tiles 0,1; drain tile 0 only (tile 1 stays in flight)
  STG_A(0, 0); STG_B(0, 0);
  STG_A(1, 1); STG_B(1, 1);
  asm volatile("s_waitcnt vmcnt(4)" ::: "memory");
  __builtin_amdgcn_s_barrier();
  __builtin_amdgcn_sched_barrier(0);

#pragma unroll
  for (int i = 0; i < 16; ++i) {
    const int rb = i % 3;  // compile-time after unroll

#pragma unroll
    for (int m = 0; m < 4; ++m)
      a[m] = *(const short8*)&Asm[rb * 4096 + eaA[m]];
#pragma unroll
    for (int n = 0; n < 4; ++n)
      bfr[n] = *(const short8*)&Bsm[rb * 4096 + eaB[n]];

    // stage tile i+2 into ring slot (i+2)%3 (4 loads/thread)
    if (i < 14) {
      const int sb = (i + 2) % 3;
      STG_A(sb, i + 2);
      STG_B(sb, i + 2);
    }

    __builtin_amdgcn_s_barrier();        // MID
    asm volatile("s_waitcnt lgkmcnt(0)" ::: "memory");
    __builtin_amdgcn_sched_barrier(0);

    __builtin_amdgcn_s_setprio(1);
#pragma unroll
    for (int m = 0; m < 4; ++m)
#pragma unroll
      for (int n = 0; n < 4; ++n)
        acc[m][n] = __builtin_amdgcn_mfma_f32_16x16x32_bf16(
            a[m], bfr[n], acc[m][n], 0, 0, 0);
    __builtin_amdgcn_s_setprio(0);

    // counted wait: drains phase i-1's loads (= tile i+1, read next phase)
    if (i < 14) {
      asm volatile("s_waitcnt vmcnt(4)" ::: "memory");
    } else if (i == 14) {
      asm volatile("s_waitcnt vmcnt(0)" ::: "memory");  // tail drain
    }
    __builtin_amdgcn_s_barrier();        // END
    __builtin_amdgcn_sched_barrier(0);
  }

  asm volatile("s_waitcnt vmcnt(0) lgkmcnt(0)" ::: "memory");

  // ---- epilogue: exp2 in place
  const float cs = scale[0];
  const int hi4 = g * 4;
  const int rbase = bi * 128 + wr * 64 + hi4;
  const int cbase = bj * 128 + wc * 64 + ln15;

  float scol[4];
#pragma unroll
  for (int n = 0; n < 4; ++n) scol[n] = sq[cbase + n * 16];

#pragma unroll
  for (int m = 0; m < 4; ++m) {
#pragma unroll
    for (int r = 0; r < 4; ++r) {
      const float sr = sq[rbase + m * 16 + r];
#pragma unroll
      for (int n = 0; n < 4; ++n) {
        float d2 = sr + scol[n] - 2.f * acc[m][n][r];
        d2 = fmaxf(d2, 0.f);
        acc[m][n][r] = EXP2F(-d2 * cs);
      }
    }
  }

  // ---- store 1: direct tile (bi, bj), nontemporal scalar stores
#pragma unroll
  for (int m = 0; m < 4; ++m) {
#pragma unroll
    for (int r = 0; r < 4; ++r) {
      const size_t rowoff = (size_t)(rbase + m * 16 + r) * MROWS;
#pragma unroll
      for (int n = 0; n < 4; ++n)
        __builtin_nontemporal_store(acc[m][n][r],
                                    &out[rowoff + cbase + n * 16]);
    }
  }

  // ---- store 2: transposed tile (bj, bi) via LDS bounce, nt stores
  if (bi != bj) {
#pragma unroll 1
    for (int cc = 0; cc < 2; ++cc) {       // two 64-col chunks of the T-tile
      __syncthreads();
      if (wc == cc) {                       // 2 waves own this chunk
#pragma unroll
        for (int m = 0; m < 4; ++m) {
#pragma unroll
          for (int n = 0; n < 4; ++n) {
            const int c_loc = n * 16 + ln15;           // 0..63
            const int r_loc = wr * 64 + m * 16 + hi4;  // 0..127, %4==0
            *(float4*)&tr[c_loc * 132 + r_loc] = *(float4*)&acc[m][n];
          }
        }
      }
      __syncthreads();
#pragma unroll
      for (int rr = 0; rr < 16; ++rr) {     // 4 waves x 16 rows
        const int row = w * 16 + rr;
        f32x2 v = *(const f32x2*)&tr[row * 132 + lane * 2];
        __builtin_nontemporal_store(
            v, (f32x2*)&out[(size_t)(bj * 128 + cc * 64 + row) * MROWS +
                            bi * 128 + lane * 2]);
      }
    }
  }
}

// ---------------------------------------------------------------------------
extern "C" void kernel_launch(void* const* d_in, const int* in_sizes, int n_in,
                              void* d_out, int out_size, void* d_ws,
                              size_t ws_size, hipStream_t stream) {
  (void)in_sizes; (void)n_in; (void)out_size; (void)ws_size;
  const float* X = (const float*)d_in[0];
  float* out = (float*)d_out;
  char* ws = (char*)d_ws;

  // ws layout (non-overlapping)
  unsigned short* Xb  = (unsigned short*)ws;               // [0, 8388608)
  float* sq           = (float*)(ws + 8388608);            // [8388608, 8421376)
  float* svec_part    = (float*)(ws + 8421376);            // [8421376, 8945664)
  float* sumsq_part   = (float*)(ws + 8945664);            // [8945664, 8946688)
  float* svec2        = (float*)(ws + 8946688);            // [8946688, 9077760)
  float* sumsq2       = (float*)(ws + 9077760);            // [9077760, 9078016)
  float* scale        = (float*)(ws + 9078016);            // [9078016, ...)

  hipLaunchKernelGGL(k_prep, dim3(256), dim3(256), 0, stream,
                     X, Xb, sq, svec_part, sumsq_part);
  hipLaunchKernelGGL(k_sig_a, dim3(64), dim3(512), 0, stream,
                     svec_part, sumsq_part, svec2, sumsq2);
  hipLaunchKernelGGL(k_sigma, dim3(1), dim3(256), 0, stream,
                     svec2, sumsq2, scale);
  hipLaunchKernelGGL(k_gemm, dim3(2080), dim3(256), 0, stream,
                     Xb, sq, scale, out);
}

// Round 13
// 102.135 us; speedup vs baseline: 1.2906x; 1.0465x over previous
//
#include <hip/hip_runtime.h>
#include <stdint.h>
#include <math.h>

#define MROWS 8192
#define KDIM  512

typedef __attribute__((ext_vector_type(8))) short short8;
typedef __attribute__((ext_vector_type(4))) float f32x4;

#if __has_builtin(__builtin_amdgcn_exp2f)
#define EXP2F(x) __builtin_amdgcn_exp2f(x)
#else
#define EXP2F(x) exp2f(x)
#endif

#define GL2LDS(gp, lp) __builtin_amdgcn_global_load_lds( \
    (__attribute__((address_space(1))) void*)(gp),       \
    (__attribute__((address_space(3))) void*)(lp), 16, 0, 0)

__device__ inline unsigned short f2bf_rne(float f) {
  unsigned u = __builtin_bit_cast(unsigned, f);
  unsigned r = 0x7FFFu + ((u >> 16) & 1u);
  return (unsigned short)((u + r) >> 16);
}

// Swizzle: logical (row, g) -> physical granule in a 512-granule K-step tile.
// Bijective (verified on-device R2-R11).
__device__ inline int swzP(int row, int g) {
  return (row * 4) ^ (g ^ (row & 3)) ^ (((row >> 2) & 1) << 2);
}

// ---------------------------------------------------------------------------
// Kernel 1: cast X -> bf16, row norms, partial sums for sigma^2.
// ---------------------------------------------------------------------------
__global__ __launch_bounds__(256) void k_prep(
    const float* __restrict__ X, unsigned short* __restrict__ Xb,
    float* __restrict__ sq, float* __restrict__ svec_part,
    float* __restrict__ sumsq_part) {
  __shared__ float ssv[4][512];
  __shared__ float ssq[4];
  const int tid = threadIdx.x, lane = tid & 63, w = tid >> 6;
  const int b = blockIdx.x;

  float ca[8] = {0.f, 0.f, 0.f, 0.f, 0.f, 0.f, 0.f, 0.f};
  float lss = 0.f;

  for (int rr = 0; rr < 8; ++rr) {
    const int row = b * 32 + w * 8 + rr;
    const float4* xr = (const float4*)(X + (size_t)row * KDIM);
    float4 v0 = xr[lane];
    float4 v1 = xr[64 + lane];

    ushort4 p0, p1;
    p0.x = f2bf_rne(v0.x); p0.y = f2bf_rne(v0.y);
    p0.z = f2bf_rne(v0.z); p0.w = f2bf_rne(v0.w);
    p1.x = f2bf_rne(v1.x); p1.y = f2bf_rne(v1.y);
    p1.z = f2bf_rne(v1.z); p1.w = f2bf_rne(v1.w);
    *(ushort4*)(Xb + (size_t)row * KDIM + lane * 4)       = p0;
    *(ushort4*)(Xb + (size_t)row * KDIM + 256 + lane * 4) = p1;

    float s2 = v0.x*v0.x + v0.y*v0.y + v0.z*v0.z + v0.w*v0.w
             + v1.x*v1.x + v1.y*v1.y + v1.z*v1.z + v1.w*v1.w;
    float rs = s2;
#pragma unroll
    for (int off = 32; off; off >>= 1) rs += __shfl_xor(rs, off, 64);
    if (lane == 0) sq[row] = rs;
    lss += s2;

    ca[0] += v0.x; ca[1] += v0.y; ca[2] += v0.z; ca[3] += v0.w;
    ca[4] += v1.x; ca[5] += v1.y; ca[6] += v1.z; ca[7] += v1.w;
  }

#pragma unroll
  for (int i = 0; i < 4; ++i) {
    ssv[w][lane * 4 + i]       = ca[i];
    ssv[w][256 + lane * 4 + i] = ca[4 + i];
  }
  float wsum = lss;
#pragma unroll
  for (int off = 32; off; off >>= 1) wsum += __shfl_xor(wsum, off, 64);
  if (lane == 0) ssq[w] = wsum;
  __syncthreads();

  svec_part[(size_t)b * 512 + tid] =
      ssv[0][tid] + ssv[1][tid] + ssv[2][tid] + ssv[3][tid];
  svec_part[(size_t)b * 512 + 256 + tid] =
      ssv[0][tid + 256] + ssv[1][tid + 256] + ssv[2][tid + 256] + ssv[3][tid + 256];
  if (tid == 0) sumsq_part[b] = ssq[0] + ssq[1] + ssq[2] + ssq[3];
}

// ---------------------------------------------------------------------------
// Kernel 2a: first-stage reduction of partials (64 blocks x 4 each)
// ---------------------------------------------------------------------------
__global__ __launch_bounds__(512) void k_sig_a(
    const float* __restrict__ svec_part, const float* __restrict__ sumsq_part,
    float* __restrict__ svec2, float* __restrict__ sumsq2) {
  const int tid = threadIdx.x, b = blockIdx.x;
  float s = 0.f;
#pragma unroll
  for (int k = 0; k < 4; ++k)
    s += svec_part[(size_t)(b * 4 + k) * 512 + tid];
  svec2[(size_t)b * 512 + tid] = s;
  if (tid == 0)
    sumsq2[b] = sumsq_part[b * 4] + sumsq_part[b * 4 + 1] +
                sumsq_part[b * 4 + 2] + sumsq_part[b * 4 + 3];
}

// ---------------------------------------------------------------------------
// Kernel 2b: scale = log2e / (2*sigma^2)
// ---------------------------------------------------------------------------
__global__ __launch_bounds__(256) void k_sigma(
    const float* __restrict__ svec2, const float* __restrict__ sumsq2,
    float* __restrict__ scale) {
  __shared__ float red[4];
  const int tid = threadIdx.x, lane = tid & 63, w = tid >> 6;
  float s1 = 0.f, s2 = 0.f;
#pragma unroll 4
  for (int b = 0; b < 64; ++b) {
    s1 += svec2[(size_t)b * 512 + tid];
    s2 += svec2[(size_t)b * 512 + 256 + tid];
  }
  float ss = s1 * s1 + s2 * s2;
#pragma unroll
  for (int off = 32; off; off >>= 1) ss += __shfl_xor(ss, off, 64);
  if (lane == 0) red[w] = ss;
  __syncthreads();
  if (tid == 0) {
    float sst = red[0] + red[1] + red[2] + red[3];
    float sumsq = 0.f;
#pragma unroll
    for (int b = 0; b < 64; ++b) sumsq += sumsq2[b];
    const float m = (float)MROWS;
    float meand2 = 2.f * sumsq / m - 2.f * sst / (m * m);
    float sigma2 = 1.0f * meand2;  // ALPHA = 1.0
    scale[0] = 1.4426950408889634f / (2.f * sigma2);
  }
}

// ---------------------------------------------------------------------------
// Kernel 3: SYMMETRIC 128x128-tile bf16 MFMA GEMM, 3 blocks/CU, ring-3 LDS
// (R10-proven loop). BOTH output tiles now stored via LDS bounce ->
// full-row contiguity (f32x4, 2 rows / wave-instr, 512 B runs), nt stores.
// ---------------------------------------------------------------------------
__global__ __launch_bounds__(256, 3) void k_gemm(
    const unsigned short* __restrict__ Xb, const float* __restrict__ sq,
    const float* __restrict__ scale, float* __restrict__ out) {
  __shared__ __align__(16) char smem[49152];
  unsigned short* Asm = (unsigned short*)smem;            // [3][4096] elem
  unsigned short* Bsm = (unsigned short*)(smem + 24576);  // [3][4096] elem
  float* tr = (float*)smem;                               // [64][132] bounce

  const int tid = threadIdx.x, lane = tid & 63, w = tid >> 6;
  const int wr = w >> 1, wc = w & 1;  // 2 x 2 wave grid
  const int ln15 = lane & 15, g = lane >> 4;

  // Upper-triangular unranking with XCD swizzle (2080 = 8*260, bijective)
  const int blk = blockIdx.x;
  const int t = (blk & 7) * 260 + (blk >> 3);
  int j = (int)((sqrtf(8.0f * (float)t + 1.0f) - 1.0f) * 0.5f);
  while ((j + 1) * (j + 2) / 2 <= t) ++j;
  while (j * (j + 1) / 2 > t) --j;
  const int bi = t - j * (j + 1) / 2;  // bi <= bj
  const int bj = j;

  // stage-source: thread covers physical granules P = w*128 + q*64 + lane
  const unsigned short* XbA = Xb + (size_t)bi * 128 * KDIM;
  const unsigned short* XbB = Xb + (size_t)bj * 128 * KDIM;
  const unsigned short* sA[2];
  const unsigned short* sB[2];
  int dOf[2];
#pragma unroll
  for (int q = 0; q < 2; ++q) {
    const int P = (w << 7) + (q << 6) + lane;
    const int row = ((P >> 3) << 1) | (((P >> 2) ^ (P >> 4)) & 1);
    const int gg = (P & 3) ^ (row & 3);
    sA[q] = XbA + row * KDIM + gg * 8;
    sB[q] = XbB + row * KDIM + gg * 8;
    dOf[q] = (w << 10) + (q << 9);  // element offset within one ring slot
  }

  // read-side swizzled element offsets within one 4096-elem tile
  int eaA[4], eaB[4];
#pragma unroll
  for (int m = 0; m < 4; ++m)
    eaA[m] = swzP(wr * 64 + m * 16 + ln15, g) * 8;
#pragma unroll
  for (int n = 0; n < 4; ++n)
    eaB[n] = swzP(wc * 64 + n * 16 + ln15, g) * 8;

  f32x4 acc[4][4] = {};
  short8 a[4], bfr[4];

#define STG_A(sb, kt)                                          \
  { GL2LDS(sA[0] + (kt) * 32, &Asm[(sb) * 4096 + dOf[0]]);     \
    GL2LDS(sA[1] + (kt) * 32, &Asm[(sb) * 4096 + dOf[1]]); }
#define STG_B(sb, kt)                                          \
  { GL2LDS(sB[0] + (kt) * 32, &Bsm[(sb) * 4096 + dOf[0]]);     \
    GL2LDS(sB[1] + (kt) * 32, &Bsm[(sb) * 4096 + dOf[1]]); }

  // prologue: stage tiles 0,1; drain tile 0 only (tile 1 stays in flight)
  STG_A(0, 0); STG_B(0, 0);
  STG_A(1, 1); STG_B(1, 1);
  asm volatile("s_waitcnt vmcnt(4)" ::: "memory");
  __builtin_amdgcn_s_barrier();
  __builtin_amdgcn_sched_barrier(0);

#pragma unroll
  for (int i = 0; i < 16; ++i) {
    const int rb = i % 3;  // compile-time after unroll

#pragma unroll
    for (int m = 0; m < 4; ++m)
      a[m] = *(const short8*)&Asm[rb * 4096 + eaA[m]];
#pragma unroll
    for (int n = 0; n < 4; ++n)
      bfr[n] = *(const short8*)&Bsm[rb * 4096 + eaB[n]];

    // stage tile i+2 into ring slot (i+2)%3 (4 loads/thread)
    if (i < 14) {
      const int sb = (i + 2) % 3;
      STG_A(sb, i + 2);
      STG_B(sb, i + 2);
    }

    __builtin_amdgcn_s_barrier();        // MID
    asm volatile("s_waitcnt lgkmcnt(0)" ::: "memory");
    __builtin_amdgcn_sched_barrier(0);

    __builtin_amdgcn_s_setprio(1);
#pragma unroll
    for (int m = 0; m < 4; ++m)
#pragma unroll
      for (int n = 0; n < 4; ++n)
        acc[m][n] = __builtin_amdgcn_mfma_f32_16x16x32_bf16(
            a[m], bfr[n], acc[m][n], 0, 0, 0);
    __builtin_amdgcn_s_setprio(0);

    // counted wait: drains phase i-1's loads (= tile i+1, read next phase)
    if (i < 14) {
      asm volatile("s_waitcnt vmcnt(4)" ::: "memory");
    } else if (i == 14) {
      asm volatile("s_waitcnt vmcnt(0)" ::: "memory");  // tail drain
    }
    __builtin_amdgcn_s_barrier();        // END
    __builtin_amdgcn_sched_barrier(0);
  }

  asm volatile("s_waitcnt vmcnt(0) lgkmcnt(0)" ::: "memory");

  // ---- epilogue: exp2 in place
  const float cs = scale[0];
  const int hi4 = g * 4;
  const int rbase = bi * 128 + wr * 64 + hi4;
  const int cbase = bj * 128 + wc * 64 + ln15;

  float scol[4];
#pragma unroll
  for (int n = 0; n < 4; ++n) scol[n] = sq[cbase + n * 16];

#pragma unroll
  for (int m = 0; m < 4; ++m) {
#pragma unroll
    for (int r = 0; r < 4; ++r) {
      const float sr = sq[rbase + m * 16 + r];
#pragma unroll
      for (int n = 0; n < 4; ++n) {
        float d2 = sr + scol[n] - 2.f * acc[m][n][r];
        d2 = fmaxf(d2, 0.f);
        acc[m][n][r] = EXP2F(-d2 * cs);
      }
    }
  }

  // ---- store 1: direct tile (bi, bj) via LDS bounce -> contiguous rows
#pragma unroll 1
  for (int c = 0; c < 2; ++c) {            // 64-row chunks
    __syncthreads();
    if (wr == c) {                         // 2 waves hold these rows
#pragma unroll
      for (int m = 0; m < 4; ++m)
#pragma unroll
        for (int n = 0; n < 4; ++n)
#pragma unroll
          for (int r = 0; r < 4; ++r)
            tr[(m * 16 + hi4 + r) * 132 + wc * 64 + n * 16 + ln15] =
                acc[m][n][r];
    }
    __syncthreads();
#pragma unroll
    for (int rr = 0; rr < 8; ++rr) {       // 2 rows / instr, 512 B runs
      const int row = w * 16 + rr * 2 + (lane >> 5);
      f32x4 v = *(const f32x4*)&tr[row * 132 + (lane & 31) * 4];
      __builtin_nontemporal_store(
          v, (f32x4*)&out[(size_t)(bi * 128 + c * 64 + row) * MROWS +
                          bj * 128 + (lane & 31) * 4]);
    }
  }

  // ---- store 2: transposed tile (bj, bi) via LDS bounce (off-diag only)
  if (bi != bj) {
#pragma unroll 1
    for (int cc = 0; cc < 2; ++cc) {       // two 64-col chunks of the T-tile
      __syncthreads();
      if (wc == cc) {                       // 2 waves own this chunk
#pragma unroll
        for (int m = 0; m < 4; ++m) {
#pragma unroll
          for (int n = 0; n < 4; ++n) {
            const int c_loc = n * 16 + ln15;           // 0..63
            const int r_loc = wr * 64 + m * 16 + hi4;  // 0..127, %4==0
            *(f32x4*)&tr[c_loc * 132 + r_loc] = acc[m][n];
          }
        }
      }
      __syncthreads();
#pragma unroll
      for (int rr = 0; rr < 8; ++rr) {     // 2 rows / instr, 512 B runs
        const int row = w * 16 + rr * 2 + (lane >> 5);
        f32x4 v = *(const f32x4*)&tr[row * 132 + (lane & 31) * 4];
        __builtin_nontemporal_store(
            v, (f32x4*)&out[(size_t)(bj * 128 + cc * 64 + row) * MROWS +
                            bi * 128 + (lane & 31) * 4]);
      }
    }
  }
}

// ---------------------------------------------------------------------------
extern "C" void kernel_launch(void* const* d_in, const int* in_sizes, int n_in,
                              void* d_out, int out_size, void* d_ws,
                              size_t ws_size, hipStream_t stream) {
  (void)in_sizes; (void)n_in; (void)out_size; (void)ws_size;
  const float* X = (const float*)d_in[0];
  float* out = (float*)d_out;
  char* ws = (char*)d_ws;

  // ws layout (non-overlapping)
  unsigned short* Xb  = (unsigned short*)ws;               // [0, 8388608)
  float* sq           = (float*)(ws + 8388608);            // [8388608, 8421376)
  float* svec_part    = (float*)(ws + 8421376);            // [8421376, 8945664)
  float* sumsq_part   = (float*)(ws + 8945664);            // [8945664, 8946688)
  float* svec2        = (float*)(ws + 8946688);            // [8946688, 9077760)
  float* sumsq2       = (float*)(ws + 9077760);            // [9077760, 9078016)
  float* scale        = (float*)(ws + 9078016);            // [9078016, ...)

  hipLaunchKernelGGL(k_prep, dim3(256), dim3(256), 0, stream,
                     X, Xb, sq, svec_part, sumsq_part);
  hipLaunchKernelGGL(k_sig_a, dim3(64), dim3(512), 0, stream,
                     svec_part, sumsq_part, svec2, sumsq2);
  hipLaunchKernelGGL(k_sigma, dim3(1), dim3(256), 0, stream,
                     svec2, sumsq2, scale);
  hipLaunchKernelGGL(k_gemm, dim3(2080), dim3(256), 0, stream,
                     Xb, sq, scale, out);
}

// Round 14
// 101.471 us; speedup vs baseline: 1.2990x; 1.0065x over previous
//
#include <hip/hip_runtime.h>
#include <stdint.h>
#include <math.h>

#define MROWS 8192
#define KDIM  512

typedef __attribute__((ext_vector_type(8))) short short8;
typedef __attribute__((ext_vector_type(4))) float f32x4;

#if __has_builtin(__builtin_amdgcn_exp2f)
#define EXP2F(x) __builtin_amdgcn_exp2f(x)
#else
#define EXP2F(x) exp2f(x)
#endif

#define GL2LDS(gp, lp) __builtin_amdgcn_global_load_lds( \
    (__attribute__((address_space(1))) void*)(gp),       \
    (__attribute__((address_space(3))) void*)(lp), 16, 0, 0)

__device__ inline unsigned short f2bf_rne(float f) {
  unsigned u = __builtin_bit_cast(unsigned, f);
  unsigned r = 0x7FFFu + ((u >> 16) & 1u);
  return (unsigned short)((u + r) >> 16);
}

// Swizzle: logical (row, g) -> physical granule in a 512-granule K-step tile.
// Bijective (verified on-device R2-R12).
__device__ inline int swzP(int row, int g) {
  return (row * 4) ^ (g ^ (row & 3)) ^ (((row >> 2) & 1) << 2);
}

// ---------------------------------------------------------------------------
// Kernel 1: cast X -> bf16, row norms, partial sums for sigma^2.
// 256 blocks x 512 threads (8 waves x 4 rows) -- halved critical path vs R12.
// ---------------------------------------------------------------------------
__global__ __launch_bounds__(512) void k_prep(
    const float* __restrict__ X, unsigned short* __restrict__ Xb,
    float* __restrict__ sq, float* __restrict__ svec_part,
    float* __restrict__ sumsq_part) {
  __shared__ float ssv[8][512];
  __shared__ float ssq[8];
  const int tid = threadIdx.x, lane = tid & 63, w = tid >> 6;
  const int b = blockIdx.x;

  float ca[8] = {0.f, 0.f, 0.f, 0.f, 0.f, 0.f, 0.f, 0.f};
  float lss = 0.f;

  for (int rr = 0; rr < 4; ++rr) {
    const int row = b * 32 + w * 4 + rr;
    const float4* xr = (const float4*)(X + (size_t)row * KDIM);
    float4 v0 = xr[lane];
    float4 v1 = xr[64 + lane];

    ushort4 p0, p1;
    p0.x = f2bf_rne(v0.x); p0.y = f2bf_rne(v0.y);
    p0.z = f2bf_rne(v0.z); p0.w = f2bf_rne(v0.w);
    p1.x = f2bf_rne(v1.x); p1.y = f2bf_rne(v1.y);
    p1.z = f2bf_rne(v1.z); p1.w = f2bf_rne(v1.w);
    *(ushort4*)(Xb + (size_t)row * KDIM + lane * 4)       = p0;
    *(ushort4*)(Xb + (size_t)row * KDIM + 256 + lane * 4) = p1;

    float s2 = v0.x*v0.x + v0.y*v0.y + v0.z*v0.z + v0.w*v0.w
             + v1.x*v1.x + v1.y*v1.y + v1.z*v1.z + v1.w*v1.w;
    float rs = s2;
#pragma unroll
    for (int off = 32; off; off >>= 1) rs += __shfl_xor(rs, off, 64);
    if (lane == 0) sq[row] = rs;
    lss += s2;

    ca[0] += v0.x; ca[1] += v0.y; ca[2] += v0.z; ca[3] += v0.w;
    ca[4] += v1.x; ca[5] += v1.y; ca[6] += v1.z; ca[7] += v1.w;
  }

#pragma unroll
  for (int i = 0; i < 4; ++i) {
    ssv[w][lane * 4 + i]       = ca[i];
    ssv[w][256 + lane * 4 + i] = ca[4 + i];
  }
  float wsum = lss;
#pragma unroll
  for (int off = 32; off; off >>= 1) wsum += __shfl_xor(wsum, off, 64);
  if (lane == 0) ssq[w] = wsum;
  __syncthreads();

  float s = 0.f;
#pragma unroll
  for (int ww = 0; ww < 8; ++ww) s += ssv[ww][tid];
  svec_part[(size_t)b * 512 + tid] = s;
  if (tid == 0)
    sumsq_part[b] = ssq[0] + ssq[1] + ssq[2] + ssq[3] +
                    ssq[4] + ssq[5] + ssq[6] + ssq[7];
}

// ---------------------------------------------------------------------------
// Kernel 2a: first-stage reduction of partials (64 blocks x 4 each)
// ---------------------------------------------------------------------------
__global__ __launch_bounds__(512) void k_sig_a(
    const float* __restrict__ svec_part, const float* __restrict__ sumsq_part,
    float* __restrict__ svec2, float* __restrict__ sumsq2) {
  const int tid = threadIdx.x, b = blockIdx.x;
  float s = 0.f;
#pragma unroll
  for (int k = 0; k < 4; ++k)
    s += svec_part[(size_t)(b * 4 + k) * 512 + tid];
  svec2[(size_t)b * 512 + tid] = s;
  if (tid == 0)
    sumsq2[b] = sumsq_part[b * 4] + sumsq_part[b * 4 + 1] +
                sumsq_part[b * 4 + 2] + sumsq_part[b * 4 + 3];
}

// ---------------------------------------------------------------------------
// Kernel 2b: scale = log2e / (2*sigma^2)
// ---------------------------------------------------------------------------
__global__ __launch_bounds__(256) void k_sigma(
    const float* __restrict__ svec2, const float* __restrict__ sumsq2,
    float* __restrict__ scale) {
  __shared__ float red[4];
  const int tid = threadIdx.x, lane = tid & 63, w = tid >> 6;
  float s1 = 0.f, s2 = 0.f;
#pragma unroll 4
  for (int b = 0; b < 64; ++b) {
    s1 += svec2[(size_t)b * 512 + tid];
    s2 += svec2[(size_t)b * 512 + 256 + tid];
  }
  float ss = s1 * s1 + s2 * s2;
#pragma unroll
  for (int off = 32; off; off >>= 1) ss += __shfl_xor(ss, off, 64);
  if (lane == 0) red[w] = ss;
  __syncthreads();
  if (tid == 0) {
    float sst = red[0] + red[1] + red[2] + red[3];
    float sumsq = 0.f;
#pragma unroll
    for (int b = 0; b < 64; ++b) sumsq += sumsq2[b];
    const float m = (float)MROWS;
    float meand2 = 2.f * sumsq / m - 2.f * sst / (m * m);
    float sigma2 = 1.0f * meand2;  // ALPHA = 1.0
    scale[0] = 1.4426950408889634f / (2.f * sigma2);
  }
}

// ---------------------------------------------------------------------------
// Kernel 3: SYMMETRIC 128x128-tile bf16 MFMA GEMM, 3 blocks/CU, ring-3 LDS.
// SINGLE barrier per phase (MID removed -- WAR carried by END barrier via
// each wave's lgkmcnt(0) before it; RAW by per-wave vmcnt(4) + END).
// Epilogue: LDS-bounce both tiles, f32x4 rows, nt stores (R12-proven).
// ---------------------------------------------------------------------------
__global__ __launch_bounds__(256, 3) void k_gemm(
    const unsigned short* __restrict__ Xb, const float* __restrict__ sq,
    const float* __restrict__ scale, float* __restrict__ out) {
  __shared__ __align__(16) char smem[49152];
  unsigned short* Asm = (unsigned short*)smem;            // [3][4096] elem
  unsigned short* Bsm = (unsigned short*)(smem + 24576);  // [3][4096] elem
  float* tr = (float*)smem;                               // [64][132] bounce

  const int tid = threadIdx.x, lane = tid & 63, w = tid >> 6;
  const int wr = w >> 1, wc = w & 1;  // 2 x 2 wave grid
  const int ln15 = lane & 15, g = lane >> 4;

  // Upper-triangular unranking with XCD swizzle (2080 = 8*260, bijective)
  const int blk = blockIdx.x;
  const int t = (blk & 7) * 260 + (blk >> 3);
  int j = (int)((sqrtf(8.0f * (float)t + 1.0f) - 1.0f) * 0.5f);
  while ((j + 1) * (j + 2) / 2 <= t) ++j;
  while (j * (j + 1) / 2 > t) --j;
  const int bi = t - j * (j + 1) / 2;  // bi <= bj
  const int bj = j;

  // stage-source: thread covers physical granules P = w*128 + q*64 + lane
  const unsigned short* XbA = Xb + (size_t)bi * 128 * KDIM;
  const unsigned short* XbB = Xb + (size_t)bj * 128 * KDIM;
  const unsigned short* sA[2];
  const unsigned short* sB[2];
  int dOf[2];
#pragma unroll
  for (int q = 0; q < 2; ++q) {
    const int P = (w << 7) + (q << 6) + lane;
    const int row = ((P >> 3) << 1) | (((P >> 2) ^ (P >> 4)) & 1);
    const int gg = (P & 3) ^ (row & 3);
    sA[q] = XbA + row * KDIM + gg * 8;
    sB[q] = XbB + row * KDIM + gg * 8;
    dOf[q] = (w << 10) + (q << 9);  // element offset within one ring slot
  }

  // read-side swizzled element offsets within one 4096-elem tile
  int eaA[4], eaB[4];
#pragma unroll
  for (int m = 0; m < 4; ++m)
    eaA[m] = swzP(wr * 64 + m * 16 + ln15, g) * 8;
#pragma unroll
  for (int n = 0; n < 4; ++n)
    eaB[n] = swzP(wc * 64 + n * 16 + ln15, g) * 8;

  f32x4 acc[4][4] = {};
  short8 a[4], bfr[4];

#define STG_A(sb, kt)                                          \
  { GL2LDS(sA[0] + (kt) * 32, &Asm[(sb) * 4096 + dOf[0]]);     \
    GL2LDS(sA[1] + (kt) * 32, &Asm[(sb) * 4096 + dOf[1]]); }
#define STG_B(sb, kt)                                          \
  { GL2LDS(sB[0] + (kt) * 32, &Bsm[(sb) * 4096 + dOf[0]]);     \
    GL2LDS(sB[1] + (kt) * 32, &Bsm[(sb) * 4096 + dOf[1]]); }

  // prologue: stage tiles 0,1; drain tile 0 only (tile 1 stays in flight)
  STG_A(0, 0); STG_B(0, 0);
  STG_A(1, 1); STG_B(1, 1);
  asm volatile("s_waitcnt vmcnt(4)" ::: "memory");
  __builtin_amdgcn_s_barrier();
  __builtin_amdgcn_sched_barrier(0);

#pragma unroll
  for (int i = 0; i < 16; ++i) {
    const int rb = i % 3;  // compile-time after unroll

#pragma unroll
    for (int m = 0; m < 4; ++m)
      a[m] = *(const short8*)&Asm[rb * 4096 + eaA[m]];
#pragma unroll
    for (int n = 0; n < 4; ++n)
      bfr[n] = *(const short8*)&Bsm[rb * 4096 + eaB[n]];

    // stage tile i+2 into ring slot (i+2)%3 (4 loads/thread)
    if (i < 14) {
      const int sb = (i + 2) % 3;
      STG_A(sb, i + 2);
      STG_B(sb, i + 2);
    }

    // per-wave: my ds_reads must land before my MFMA (rule #18 fence)
    asm volatile("s_waitcnt lgkmcnt(0)" ::: "memory");
    __builtin_amdgcn_sched_barrier(0);

    __builtin_amdgcn_s_setprio(1);
#pragma unroll
    for (int m = 0; m < 4; ++m)
#pragma unroll
      for (int n = 0; n < 4; ++n)
        acc[m][n] = __builtin_amdgcn_mfma_f32_16x16x32_bf16(
            a[m], bfr[n], acc[m][n], 0, 0, 0);
    __builtin_amdgcn_s_setprio(0);

    // counted wait: drains phase i-1's loads (= tile i+1, read next phase)
    if (i < 14) {
      asm volatile("s_waitcnt vmcnt(4)" ::: "memory");
    } else if (i == 14) {
      asm volatile("s_waitcnt vmcnt(0)" ::: "memory");  // tail drain
    }
    __builtin_amdgcn_s_barrier();        // single END barrier per phase
    __builtin_amdgcn_sched_barrier(0);
  }

  asm volatile("s_waitcnt vmcnt(0) lgkmcnt(0)" ::: "memory");

  // ---- epilogue: exp2 in place
  const float cs = scale[0];
  const int hi4 = g * 4;
  const int rbase = bi * 128 + wr * 64 + hi4;
  const int cbase = bj * 128 + wc * 64 + ln15;

  float scol[4];
#pragma unroll
  for (int n = 0; n < 4; ++n) scol[n] = sq[cbase + n * 16];

#pragma unroll
  for (int m = 0; m < 4; ++m) {
#pragma unroll
    for (int r = 0; r < 4; ++r) {
      const float sr = sq[rbase + m * 16 + r];
#pragma unroll
      for (int n = 0; n < 4; ++n) {
        float d2 = sr + scol[n] - 2.f * acc[m][n][r];
        d2 = fmaxf(d2, 0.f);
        acc[m][n][r] = EXP2F(-d2 * cs);
      }
    }
  }

  // ---- store 1: direct tile (bi, bj) via LDS bounce -> contiguous rows
#pragma unroll 1
  for (int c = 0; c < 2; ++c) {            // 64-row chunks
    __syncthreads();
    if (wr == c) {                         // 2 waves hold these rows
#pragma unroll
      for (int m = 0; m < 4; ++m)
#pragma unroll
        for (int n = 0; n < 4; ++n)
#pragma unroll
          for (int r = 0; r < 4; ++r)
            tr[(m * 16 + hi4 + r) * 132 + wc * 64 + n * 16 + ln15] =
                acc[m][n][r];
    }
    __syncthreads();
#pragma unroll
    for (int rr = 0; rr < 8; ++rr) {       // 2 rows / instr, 512 B runs
      const int row = w * 16 + rr * 2 + (lane >> 5);
      f32x4 v = *(const f32x4*)&tr[row * 132 + (lane & 31) * 4];
      __builtin_nontemporal_store(
          v, (f32x4*)&out[(size_t)(bi * 128 + c * 64 + row) * MROWS +
                          bj * 128 + (lane & 31) * 4]);
    }
  }

  // ---- store 2: transposed tile (bj, bi) via LDS bounce (off-diag only)
  if (bi != bj) {
#pragma unroll 1
    for (int cc = 0; cc < 2; ++cc) {       // two 64-col chunks of the T-tile
      __syncthreads();
      if (wc == cc) {                       // 2 waves own this chunk
#pragma unroll
        for (int m = 0; m < 4; ++m) {
#pragma unroll
          for (int n = 0; n < 4; ++n) {
            const int c_loc = n * 16 + ln15;           // 0..63
            const int r_loc = wr * 64 + m * 16 + hi4;  // 0..127, %4==0
            *(f32x4*)&tr[c_loc * 132 + r_loc] = acc[m][n];
          }
        }
      }
      __syncthreads();
#pragma unroll
      for (int rr = 0; rr < 8; ++rr) {     // 2 rows / instr, 512 B runs
        const int row = w * 16 + rr * 2 + (lane >> 5);
        f32x4 v = *(const f32x4*)&tr[row * 132 + (lane & 31) * 4];
        __builtin_nontemporal_store(
            v, (f32x4*)&out[(size_t)(bj * 128 + cc * 64 + row) * MROWS +
                            bi * 128 + (lane & 31) * 4]);
      }
    }
  }
}

// ---------------------------------------------------------------------------
extern "C" void kernel_launch(void* const* d_in, const int* in_sizes, int n_in,
                              void* d_out, int out_size, void* d_ws,
                              size_t ws_size, hipStream_t stream) {
  (void)in_sizes; (void)n_in; (void)out_size; (void)ws_size;
  const float* X = (const float*)d_in[0];
  float* out = (float*)d_out;
  char* ws = (char*)d_ws;

  // ws layout (non-overlapping)
  unsigned short* Xb  = (unsigned short*)ws;               // [0, 8388608)
  float* sq           = (float*)(ws + 8388608);            // [8388608, 8421376)
  float* svec_part    = (float*)(ws + 8421376);            // [8421376, 8945664)
  float* sumsq_part   = (float*)(ws + 8945664);            // [8945664, 8946688)
  float* svec2        = (float*)(ws + 8946688);            // [8946688, 9077760)
  float* sumsq2       = (float*)(ws + 9077760);            // [9077760, 9078016)
  float* scale        = (float*)(ws + 9078016);            // [9078016, ...)

  hipLaunchKernelGGL(k_prep, dim3(256), dim3(512), 0, stream,
                     X, Xb, sq, svec_part, sumsq_part);
  hipLaunchKernelGGL(k_sig_a, dim3(64), dim3(512), 0, stream,
                     svec_part, sumsq_part, svec2, sumsq2);
  hipLaunchKernelGGL(k_sigma, dim3(1), dim3(256), 0, stream,
                     svec2, sumsq2, scale);
  hipLaunchKernelGGL(k_gemm, dim3(2080), dim3(256), 0, stream,
                     Xb, sq, scale, out);
}

// Round 16
// 90.917 us; speedup vs baseline: 1.4498x; 1.1161x over previous
//
#include <hip/hip_runtime.h>
#include <stdint.h>
#include <math.h>

#define MROWS 8192
#define KDIM  512

typedef __attribute__((ext_vector_type(8))) short short8;
typedef __attribute__((ext_vector_type(4))) float f32x4;

#if __has_builtin(__builtin_amdgcn_exp2f)
#define EXP2F(x) __builtin_amdgcn_exp2f(x)
#else
#define EXP2F(x) exp2f(x)
#endif

#define GL2LDS(gp, lp) __builtin_amdgcn_global_load_lds( \
    (__attribute__((address_space(1))) void*)(gp),       \
    (__attribute__((address_space(3))) void*)(lp), 16, 0, 0)

__device__ inline unsigned short f2bf_rne(float f) {
  unsigned u = __builtin_bit_cast(unsigned, f);
  unsigned r = 0x7FFFu + ((u >> 16) & 1u);
  return (unsigned short)((u + r) >> 16);
}

// Swizzle: logical (row, g) -> physical granule in a 512-granule K-step tile.
// Bijective (verified on-device R2-R13).
__device__ inline int swzP(int row, int g) {
  return (row * 4) ^ (g ^ (row & 3)) ^ (((row >> 2) & 1) << 2);
}

// ---------------------------------------------------------------------------
// Kernel 1: cast X -> bf16, row norms, partial sums for sigma^2.
// ---------------------------------------------------------------------------
__global__ __launch_bounds__(512) void k_prep(
    const float* __restrict__ X, unsigned short* __restrict__ Xb,
    float* __restrict__ sq, float* __restrict__ svec_part,
    float* __restrict__ sumsq_part) {
  __shared__ float ssv[8][512];
  __shared__ float ssq[8];
  const int tid = threadIdx.x, lane = tid & 63, w = tid >> 6;
  const int b = blockIdx.x;

  float ca[8] = {0.f, 0.f, 0.f, 0.f, 0.f, 0.f, 0.f, 0.f};
  float lss = 0.f;

  for (int rr = 0; rr < 4; ++rr) {
    const int row = b * 32 + w * 4 + rr;
    const float4* xr = (const float4*)(X + (size_t)row * KDIM);
    float4 v0 = xr[lane];
    float4 v1 = xr[64 + lane];

    ushort4 p0, p1;
    p0.x = f2bf_rne(v0.x); p0.y = f2bf_rne(v0.y);
    p0.z = f2bf_rne(v0.z); p0.w = f2bf_rne(v0.w);
    p1.x = f2bf_rne(v1.x); p1.y = f2bf_rne(v1.y);
    p1.z = f2bf_rne(v1.z); p1.w = f2bf_rne(v1.w);
    *(ushort4*)(Xb + (size_t)row * KDIM + lane * 4)       = p0;
    *(ushort4*)(Xb + (size_t)row * KDIM + 256 + lane * 4) = p1;

    float s2 = v0.x*v0.x + v0.y*v0.y + v0.z*v0.z + v0.w*v0.w
             + v1.x*v1.x + v1.y*v1.y + v1.z*v1.z + v1.w*v1.w;
    float rs = s2;
#pragma unroll
    for (int off = 32; off; off >>= 1) rs += __shfl_xor(rs, off, 64);
    if (lane == 0) sq[row] = rs;
    lss += s2;

    ca[0] += v0.x; ca[1] += v0.y; ca[2] += v0.z; ca[3] += v0.w;
    ca[4] += v1.x; ca[5] += v1.y; ca[6] += v1.z; ca[7] += v1.w;
  }

#pragma unroll
  for (int i = 0; i < 4; ++i) {
    ssv[w][lane * 4 + i]       = ca[i];
    ssv[w][256 + lane * 4 + i] = ca[4 + i];
  }
  float wsum = lss;
#pragma unroll
  for (int off = 32; off; off >>= 1) wsum += __shfl_xor(wsum, off, 64);
  if (lane == 0) ssq[w] = wsum;
  __syncthreads();

  float s = 0.f;
#pragma unroll
  for (int ww = 0; ww < 8; ++ww) s += ssv[ww][tid];
  svec_part[(size_t)b * 512 + tid] = s;
  if (tid == 0)
    sumsq_part[b] = ssq[0] + ssq[1] + ssq[2] + ssq[3] +
                    ssq[4] + ssq[5] + ssq[6] + ssq[7];
}

// ---------------------------------------------------------------------------
// Kernel 2a: first-stage reduction of partials (64 blocks x 4 each)
// ---------------------------------------------------------------------------
__global__ __launch_bounds__(512) void k_sig_a(
    const float* __restrict__ svec_part, const float* __restrict__ sumsq_part,
    float* __restrict__ svec2, float* __restrict__ sumsq2) {
  const int tid = threadIdx.x, b = blockIdx.x;
  float s = 0.f;
#pragma unroll
  for (int k = 0; k < 4; ++k)
    s += svec_part[(size_t)(b * 4 + k) * 512 + tid];
  svec2[(size_t)b * 512 + tid] = s;
  if (tid == 0)
    sumsq2[b] = sumsq_part[b * 4] + sumsq_part[b * 4 + 1] +
                sumsq_part[b * 4 + 2] + sumsq_part[b * 4 + 3];
}

// ---------------------------------------------------------------------------
// Kernel 2b: scale = log2e / (2*sigma^2)
// ---------------------------------------------------------------------------
__global__ __launch_bounds__(256) void k_sigma(
    const float* __restrict__ svec2, const float* __restrict__ sumsq2,
    float* __restrict__ scale) {
  __shared__ float red[4];
  const int tid = threadIdx.x, lane = tid & 63, w = tid >> 6;
  float s1 = 0.f, s2 = 0.f;
#pragma unroll 4
  for (int b = 0; b < 64; ++b) {
    s1 += svec2[(size_t)b * 512 + tid];
    s2 += svec2[(size_t)b * 512 + 256 + tid];
  }
  float ss = s1 * s1 + s2 * s2;
#pragma unroll
  for (int off = 32; off; off >>= 1) ss += __shfl_xor(ss, off, 64);
  if (lane == 0) red[w] = ss;
  __syncthreads();
  if (tid == 0) {
    float sst = red[0] + red[1] + red[2] + red[3];
    float sumsq = 0.f;
#pragma unroll
    for (int b = 0; b < 64; ++b) sumsq += sumsq2[b];
    const float m = (float)MROWS;
    float meand2 = 2.f * sumsq / m - 2.f * sst / (m * m);
    float sigma2 = 1.0f * meand2;  // ALPHA = 1.0
    scale[0] = 1.4426950408889634f / (2.f * sigma2);
  }
}

// ---------------------------------------------------------------------------
// Kernel 3: SYMMETRIC 128x128-tile bf16 MFMA GEMM, 3 blocks/CU, ring-3 LDS
// (R13-proven loop + epilogue). Super-blocked tile ordering for L2 reuse;
// R14's SJ-unranking typo fixed (sp=3 must map to (1,2), sp=4 to (1,3)).
// ---------------------------------------------------------------------------
__global__ __launch_bounds__(256, 3) void k_gemm(
    const unsigned short* __restrict__ Xb, const float* __restrict__ sq,
    const float* __restrict__ scale, float* __restrict__ out) {
  __shared__ __align__(16) char smem[49152];
  unsigned short* Asm = (unsigned short*)smem;            // [3][4096] elem
  unsigned short* Bsm = (unsigned short*)(smem + 24576);  // [3][4096] elem
  float* tr = (float*)smem;                               // [64][132] bounce

  const int tid = threadIdx.x, lane = tid & 63, w = tid >> 6;
  const int wr = w >> 1, wc = w & 1;  // 2 x 2 wave grid
  const int ln15 = lane & 15, g = lane >> 4;

  // XCD swizzle (2080 = 8*260, bijective) + super-block unranking
  const int blk = blockIdx.x;
  const int r = (blk & 7) * 260 + (blk >> 3);
  int bi, bj;
  if (r < 1536) {
    // off-diagonal super-pairs (SI<SJ), 256 tile-pairs each
    const int sp = r >> 8;          // 0..5 -> (0,1),(0,2),(0,3),(1,2),(1,3),(2,3)
    const int inner = r & 255;
    const int SI = (sp < 3) ? 0 : ((sp < 5) ? 1 : 2);
    const int SJ = (sp < 3) ? sp + 1 : ((sp < 5) ? sp - 1 : 3);  // FIXED
    bi = SI * 16 + (inner & 15);
    bj = SJ * 16 + (inner >> 4);
  } else {
    // diagonal super-pairs: triangular 136 pairs within one 16-super
    const int rd = r - 1536;
    const int sd = rd / 136;
    const int k = rd - sd * 136;
    int b = (int)((sqrtf(8.0f * (float)k + 1.0f) - 1.0f) * 0.5f);
    while ((b + 1) * (b + 2) / 2 <= k) ++b;
    while (b * (b + 1) / 2 > k) --b;
    const int a = k - b * (b + 1) / 2;   // a <= b
    bi = sd * 16 + a;
    bj = sd * 16 + b;
  }

  // stage-source: thread covers physical granules P = w*128 + q*64 + lane
  const unsigned short* XbA = Xb + (size_t)bi * 128 * KDIM;
  const unsigned short* XbB = Xb + (size_t)bj * 128 * KDIM;
  const unsigned short* sA[2];
  const unsigned short* sB[2];
  int dOf[2];
#pragma unroll
  for (int q = 0; q < 2; ++q) {
    const int P = (w << 7) + (q << 6) + lane;
    const int row = ((P >> 3) << 1) | (((P >> 2) ^ (P >> 4)) & 1);
    const int gg = (P & 3) ^ (row & 3);
    sA[q] = XbA + row * KDIM + gg * 8;
    sB[q] = XbB + row * KDIM + gg * 8;
    dOf[q] = (w << 10) + (q << 9);  // element offset within one ring slot
  }

  // read-side swizzled element offsets within one 4096-elem tile
  int eaA[4], eaB[4];
#pragma unroll
  for (int m = 0; m < 4; ++m)
    eaA[m] = swzP(wr * 64 + m * 16 + ln15, g) * 8;
#pragma unroll
  for (int n = 0; n < 4; ++n)
    eaB[n] = swzP(wc * 64 + n * 16 + ln15, g) * 8;

  f32x4 acc[4][4] = {};
  short8 a[4], bfr[4];

#define STG_A(sb, kt)                                          \
  { GL2LDS(sA[0] + (kt) * 32, &Asm[(sb) * 4096 + dOf[0]]);     \
    GL2LDS(sA[1] + (kt) * 32, &Asm[(sb) * 4096 + dOf[1]]); }
#define STG_B(sb, kt)                                          \
  { GL2LDS(sB[0] + (kt) * 32, &Bsm[(sb) * 4096 + dOf[0]]);     \
    GL2LDS(sB[1] + (kt) * 32, &Bsm[(sb) * 4096 + dOf[1]]); }

  // prologue: stage tiles 0,1; drain tile 0 only (tile 1 stays in flight)
  STG_A(0, 0); STG_B(0, 0);
  STG_A(1, 1); STG_B(1, 1);
  asm volatile("s_waitcnt vmcnt(4)" ::: "memory");
  __builtin_amdgcn_s_barrier();
  __builtin_amdgcn_sched_barrier(0);

#pragma unroll
  for (int i = 0; i < 16; ++i) {
    const int rb = i % 3;  // compile-time after unroll

#pragma unroll
    for (int m = 0; m < 4; ++m)
      a[m] = *(const short8*)&Asm[rb * 4096 + eaA[m]];
#pragma unroll
    for (int n = 0; n < 4; ++n)
      bfr[n] = *(const short8*)&Bsm[rb * 4096 + eaB[n]];

    // stage tile i+2 into ring slot (i+2)%3 (4 loads/thread)
    if (i < 14) {
      const int sb = (i + 2) % 3;
      STG_A(sb, i + 2);
      STG_B(sb, i + 2);
    }

    // per-wave: my ds_reads must land before my MFMA (rule #18 fence)
    asm volatile("s_waitcnt lgkmcnt(0)" ::: "memory");
    __builtin_amdgcn_sched_barrier(0);

    __builtin_amdgcn_s_setprio(1);
#pragma unroll
    for (int m = 0; m < 4; ++m)
#pragma unroll
      for (int n = 0; n < 4; ++n)
        acc[m][n] = __builtin_amdgcn_mfma_f32_16x16x32_bf16(
            a[m], bfr[n], acc[m][n], 0, 0, 0);
    __builtin_amdgcn_s_setprio(0);

    // counted wait: drains phase i-1's loads (= tile i+1, read next phase)
    if (i < 14) {
      asm volatile("s_waitcnt vmcnt(4)" ::: "memory");
    } else if (i == 14) {
      asm volatile("s_waitcnt vmcnt(0)" ::: "memory");  // tail drain
    }
    __builtin_amdgcn_s_barrier();        // single END barrier per phase
    __builtin_amdgcn_sched_barrier(0);
  }

  asm volatile("s_waitcnt vmcnt(0) lgkmcnt(0)" ::: "memory");

  // ---- epilogue: exp2 in place
  const float cs = scale[0];
  const int hi4 = g * 4;
  const int rbase = bi * 128 + wr * 64 + hi4;
  const int cbase = bj * 128 + wc * 64 + ln15;

  float scol[4];
#pragma unroll
  for (int n = 0; n < 4; ++n) scol[n] = sq[cbase + n * 16];

#pragma unroll
  for (int m = 0; m < 4; ++m) {
#pragma unroll
    for (int r2 = 0; r2 < 4; ++r2) {
      const float sr = sq[rbase + m * 16 + r2];
#pragma unroll
      for (int n = 0; n < 4; ++n) {
        float d2 = sr + scol[n] - 2.f * acc[m][n][r2];
        d2 = fmaxf(d2, 0.f);
        acc[m][n][r2] = EXP2F(-d2 * cs);
      }
    }
  }

  // ---- store 1: direct tile (bi, bj) via LDS bounce -> contiguous rows
#pragma unroll 1
  for (int c = 0; c < 2; ++c) {            // 64-row chunks
    __syncthreads();
    if (wr == c) {                         // 2 waves hold these rows
#pragma unroll
      for (int m = 0; m < 4; ++m)
#pragma unroll
        for (int n = 0; n < 4; ++n)
#pragma unroll
          for (int r2 = 0; r2 < 4; ++r2)
            tr[(m * 16 + hi4 + r2) * 132 + wc * 64 + n * 16 + ln15] =
                acc[m][n][r2];
    }
    __syncthreads();
#pragma unroll
    for (int rr = 0; rr < 8; ++rr) {       // 2 rows / instr, 512 B runs
      const int row = w * 16 + rr * 2 + (lane >> 5);
      f32x4 v = *(const f32x4*)&tr[row * 132 + (lane & 31) * 4];
      __builtin_nontemporal_store(
          v, (f32x4*)&out[(size_t)(bi * 128 + c * 64 + row) * MROWS +
                          bj * 128 + (lane & 31) * 4]);
    }
  }

  // ---- store 2: transposed tile (bj, bi) via LDS bounce (off-diag only)
  if (bi != bj) {
#pragma unroll 1
    for (int cc = 0; cc < 2; ++cc) {       // two 64-col chunks of the T-tile
      __syncthreads();
      if (wc == cc) {                       // 2 waves own this chunk
#pragma unroll
        for (int m = 0; m < 4; ++m) {
#pragma unroll
          for (int n = 0; n < 4; ++n) {
            const int c_loc = n * 16 + ln15;           // 0..63
            const int r_loc = wr * 64 + m * 16 + hi4;  // 0..127, %4==0
            *(f32x4*)&tr[c_loc * 132 + r_loc] = acc[m][n];
          }
        }
      }
      __syncthreads();
#pragma unroll
      for (int rr = 0; rr < 8; ++rr) {     // 2 rows / instr, 512 B runs
        const int row = w * 16 + rr * 2 + (lane >> 5);
        f32x4 v = *(const f32x4*)&tr[row * 132 + (lane & 31) * 4];
        __builtin_nontemporal_store(
            v, (f32x4*)&out[(size_t)(bj * 128 + cc * 64 + row) * MROWS +
                            bi * 128 + (lane & 31) * 4]);
      }
    }
  }
}

// ---------------------------------------------------------------------------
extern "C" void kernel_launch(void* const* d_in, const int* in_sizes, int n_in,
                              void* d_out, int out_size, void* d_ws,
                              size_t ws_size, hipStream_t stream) {
  (void)in_sizes; (void)n_in; (void)out_size; (void)ws_size;
  const float* X = (const float*)d_in[0];
  float* out = (float*)d_out;
  char* ws = (char*)d_ws;

  // ws layout (non-overlapping)
  unsigned short* Xb  = (unsigned short*)ws;               // [0, 8388608)
  float* sq           = (float*)(ws + 8388608);            // [8388608, 8421376)
  float* svec_part    = (float*)(ws + 8421376);            // [8421376, 8945664)
  float* sumsq_part   = (float*)(ws + 8945664);            // [8945664, 8946688)
  float* svec2        = (float*)(ws + 8946688);            // [8946688, 9077760)
  float* sumsq2       = (float*)(ws + 9077760);            // [9077760, 9078016)
  float* scale        = (float*)(ws + 9078016);            // [9078016, ...)

  hipLaunchKernelGGL(k_prep, dim3(256), dim3(512), 0, stream,
                     X, Xb, sq, svec_part, sumsq_part);
  hipLaunchKernelGGL(k_sig_a, dim3(64), dim3(512), 0, stream,
                     svec_part, sumsq_part, svec2, sumsq2);
  hipLaunchKernelGGL(k_sigma, dim3(1), dim3(256), 0, stream,
                     svec2, sumsq2, scale);
  hipLaunchKernelGGL(k_gemm, dim3(2080), dim3(256), 0, stream,
                     Xb, sq, scale, out);
}